// Round 11
// baseline (153.254 us; speedup 1.0000x reference)
//
#include <hip/hip_runtime.h>
#include <hip/hip_bf16.h>
#include <stdint.h>

#define B_   4
#define S_   1024
#define HID_ 1024
#define H_   16
#define DH_  64

typedef short bf16x8 __attribute__((ext_vector_type(8)));
typedef float f32x4  __attribute__((ext_vector_type(4)));
typedef unsigned int u32;
typedef unsigned short u16;

typedef u32 __attribute__((address_space(1))) as1_u32;
typedef u32 __attribute__((address_space(3))) as3_u32;

__device__ __forceinline__ f32x4 mfma16(bf16x8 a, bf16x8 b, f32x4 c) {
  return __builtin_amdgcn_mfma_f32_16x16x32_bf16(a, b, c, 0, 0, 0);
}

__device__ __forceinline__ void gload16(const void* g, void* l) {
  __builtin_amdgcn_global_load_lds((const as1_u32*)g, (as3_u32*)l, 16, 0, 0);
}

__device__ __forceinline__ u16 f2bf(float f) {
  __hip_bfloat16 h = __float2bfloat16(f);
  union { __hip_bfloat16 h; u16 u; } cv; cv.h = h; return cv.u;
}

__device__ __forceinline__ u32 cvtpk(float lo, float hi) {
  u32 r;
  asm("v_cvt_pk_bf16_f32 %0, %1, %2" : "=v"(r) : "v"(lo), "v"(hi));
  return r;
}

// stage a [NC*32 x 64] bf16 tile into LDS at byte offset bo (XOR-swizzled source)
template<int NC>
__device__ __forceinline__ void stage_tile(const u16* __restrict__ src, char* smem, int bo,
                                           int tid, int w) {
  #pragma unroll
  for (int is = 0; is < NC; ++is) {
    int o = is * 4096 + tid * 16;
    int row = o >> 7, ch = (o >> 4) & 7;
    gload16(src + (size_t)row * HID_ + ((ch ^ (row & 7)) * 8),
            smem + bo + is * 4096 + w * 1024);
  }
}

// ---------------- converts ----------------
__global__ __launch_bounds__(256) void cvt_all(
    const float* a0, const float* a1, const float* a2, const float* a3,
    const float* w0, const float* w1, const float* w2, const float* w3, const float* w4,
    u16* da0, u16* da1, u16* da2, u16* da3,
    u16* dw0, u16* dw1, u16* dw2, u16* dw3, u16* dw4) {
  int bb = blockIdx.x;
  const float* s; u16* d; size_t i;
  if (bb < 8192) {
    int t = bb * 256 + threadIdx.x;
    int sel = t >> 19;
    i = (size_t)(t & 524287) * 8;
    if (sel == 0)      { s = a0; d = da0; }
    else if (sel == 1) { s = a1; d = da1; }
    else if (sel == 2) { s = a2; d = da2; }
    else               { s = a3; d = da3; }
  } else {
    int t = (bb - 8192) * 256 + threadIdx.x;
    int sel = t >> 17;
    i = (size_t)(t & 131071) * 8;
    if (sel == 0)      { s = w0; d = dw0; }
    else if (sel == 1) { s = w1; d = dw1; }
    else if (sel == 2) { s = w2; d = dw2; }
    else if (sel == 3) { s = w3; d = dw3; }
    else               { s = w4; d = dw4; }
  }
  float4 v0 = *(const float4*)(s + i);
  float4 v1 = *(const float4*)(s + i + 4);
  uint4 r;
  r.x = cvtpk(v0.x, v0.y);
  r.y = cvtpk(v0.z, v0.w);
  r.z = cvtpk(v1.x, v1.y);
  r.w = cvtpk(v1.z, v1.w);
  *(uint4*)(d + i) = r;
}

// ---------------- fused projection GEMM: uniform 128x64 tiles, 48KB dbuf, 3 blocks/CU ----------
__global__ __launch_bounds__(256, 3) void gemm_proj(
    const u16* __restrict__ qbf, const u16* __restrict__ Wqbf,
    const u16* __restrict__ kbf, const u16* __restrict__ Wkbf,
    const u16* __restrict__ kbbf, const u16* __restrict__ Wkbbf,
    const u16* __restrict__ vbf, const u16* __restrict__ Wvbf,
    const float* __restrict__ bq, const float* __restrict__ bk,
    const float* __restrict__ bkb, const float* __restrict__ bv,
    u16* __restrict__ Qp, u16* __restrict__ KKp, u16* __restrict__ Vtp) {
  __shared__ __align__(16) char smem[49152];
  const int tid = threadIdx.x;
  const int lane = tid & 63, w = tid >> 6;
  const int g = lane >> 4, ql = lane & 15;
  const int wm = w >> 1, wn = w & 1;
  const int xr = ql & 7;
  const int xcd = blockIdx.x & 7, idx = blockIdx.x >> 3;
  const int unit = (idx < 64) ? 0 : (idx < 128) ? 1 : 2;   // 0 KK, 1 Q, 2 V
  const int id = xcd * 64 + (idx & 63);
  const int m0 = (id >> 4) * 128;
  const int n0 = (id & 15) * 64;

  const u16 *A0, *W0, *A1, *W1;
  int nkt;
  if (unit == 0)      { A0 = kbf; W0 = Wkbf; A1 = kbbf; W1 = Wkbbf; nkt = 32; }
  else if (unit == 1) { A0 = qbf; W0 = Wqbf; A1 = qbf;  W1 = Wqbf;  nkt = 16; }
  else                { A0 = vbf; W0 = Wvbf; A1 = vbf;  W1 = Wvbf;  nkt = 16; }

  f32x4 acc[4][2];
  #pragma unroll
  for (int mi = 0; mi < 4; ++mi)
    #pragma unroll
    for (int ni = 0; ni < 2; ++ni) acc[mi][ni] = f32x4{0.f, 0.f, 0.f, 0.f};

  stage_tile<4>(A0 + (size_t)m0 * HID_, smem, 0, tid, w);
  stage_tile<2>(W0 + (size_t)n0 * HID_, smem, 16384, tid, w);

  #pragma unroll 1
  for (int kt = 0; kt < nkt; ++kt) {
    const int boA = (kt & 1) ? 24576 : 0;
    const int boW = (kt & 1) ? 40960 : 16384;
    if (kt < nkt - 1) {
      int kn = kt + 1;
      const u16* As = (kn < 16) ? A0 : A1;
      const u16* Ws = (kn < 16) ? W0 : W1;
      int kk = (kn & 15) * 64;
      stage_tile<4>(As + (size_t)m0 * HID_ + kk, smem, boA ^ 24576, tid, w);
      stage_tile<2>(Ws + (size_t)n0 * HID_ + kk, smem, boW ^ (16384 ^ 40960), tid, w);
      asm volatile("s_waitcnt vmcnt(6)" ::: "memory");
    } else {
      asm volatile("s_waitcnt vmcnt(0)" ::: "memory");
    }
    __builtin_amdgcn_s_barrier();
    const char* ab = smem + boA;
    const char* wb = smem + boW;
    bf16x8 af[4][2], bfv[2][2];
    #pragma unroll
    for (int mi = 0; mi < 4; ++mi)
      #pragma unroll
      for (int c = 0; c < 2; ++c) {
        int row = wm * 64 + mi * 16 + ql;
        af[mi][c] = *(const bf16x8*)(ab + row * 128 + (((c * 4 + g) ^ xr) * 16));
      }
    #pragma unroll
    for (int ni = 0; ni < 2; ++ni)
      #pragma unroll
      for (int c = 0; c < 2; ++c) {
        int row = wn * 32 + ni * 16 + ql;
        bfv[ni][c] = *(const bf16x8*)(wb + row * 128 + (((c * 4 + g) ^ xr) * 16));
      }
    __builtin_amdgcn_s_setprio(1);
    #pragma unroll
    for (int c = 0; c < 2; ++c)
      #pragma unroll
      for (int mi = 0; mi < 4; ++mi)
        #pragma unroll
        for (int ni = 0; ni < 2; ++ni)
          acc[mi][ni] = mfma16(af[mi][c], bfv[ni][c], acc[mi][ni]);
    __builtin_amdgcn_s_setprio(0);
    __builtin_amdgcn_s_barrier();
  }

  if (unit != 2) {
    u16* outp = (unit == 0) ? KKp : Qp;
    const float osc = (unit == 1) ? 0.07216878364870322f * 1.44269504088896340f : 1.f;
    #pragma unroll
    for (int ni = 0; ni < 2; ++ni) {
      int n = n0 + wn * 32 + ni * 16 + ql;
      float bs = (unit == 0) ? (bk[n] + bkb[n]) : bq[n];
      #pragma unroll
      for (int mi = 0; mi < 4; ++mi)
        #pragma unroll
        for (int i = 0; i < 4; ++i) {
          int m = m0 + wm * 64 + mi * 16 + g * 4 + i;
          outp[(size_t)m * HID_ + n] = f2bf((acc[mi][ni][i] + bs) * osc);
        }
    }
  } else {
    char* tp = smem + w * 4096;
    #pragma unroll
    for (int ni = 0; ni < 2; ++ni) {
      int n = n0 + wn * 32 + ni * 16 + ql;
      float bs = bv[n];
      #pragma unroll
      for (int mi = 0; mi < 4; ++mi)
        #pragma unroll
        for (int i = 0; i < 4; ++i) {
          int nl = ni * 16 + ql;
          int ml = mi * 16 + g * 4 + i;
          *(u16*)(tp + nl * 128 + (((ml >> 3) ^ (nl & 7)) * 16) + (ml & 7) * 2) =
              f2bf(acc[mi][ni][i] + bs);
        }
    }
    __syncthreads();
    int r = lane >> 1, half = lane & 1;
    int n = n0 + wn * 32 + r;
    int h = n >> 6, dh = n & 63;
    int b = m0 >> 10;
    int bh = b * H_ + h;
    u16* orow = Vtp + (((size_t)(bh * DH_ + dh)) << 10) + (m0 & 1023) + wm * 64 + half * 32;
    #pragma unroll
    for (int j = 0; j < 4; ++j) {
      uint4 val = *(const uint4*)(tp + r * 128 + (((half * 4 + j) ^ (r & 7)) * 16));
      *(uint4*)(orow + j * 8) = val;
    }
  }
}

// ---------------- O GEMM (128x64 tile, bf16 in, f32 out, dbuf + counted vmcnt) ----------------
__global__ __launch_bounds__(256, 3) void gemm_o(const u16* __restrict__ A0, const u16* __restrict__ W0,
                                                 const float* __restrict__ bias0, float* __restrict__ outp) {
  __shared__ __align__(16) char smem[49152];
  const int tid = threadIdx.x;
  const int lane = tid & 63, w = tid >> 6;
  const int g = lane >> 4, ql = lane & 15;
  const int wm = w >> 1, wn = w & 1;
  const int logical = (blockIdx.x & 7) * 64 + (blockIdx.x >> 3);
  const int m0 = (logical >> 4) * 128;
  const int n0 = (logical & 15) * 64;
  const int xr = ql & 7;

  f32x4 acc[4][2];
  #pragma unroll
  for (int mi = 0; mi < 4; ++mi)
    #pragma unroll
    for (int ni = 0; ni < 2; ++ni) acc[mi][ni] = f32x4{0.f, 0.f, 0.f, 0.f};

  stage_tile<4>(A0 + (size_t)m0 * HID_, smem, 0, tid, w);
  stage_tile<2>(W0 + (size_t)n0 * HID_, smem, 16384, tid, w);

  #pragma unroll 1
  for (int kt = 0; kt < 16; ++kt) {
    const int boA = (kt & 1) ? 24576 : 0;
    const int boW = (kt & 1) ? 40960 : 16384;
    if (kt < 15) {
      int kk = (kt + 1) * 64;
      stage_tile<4>(A0 + (size_t)m0 * HID_ + kk, smem, boA ^ 24576, tid, w);
      stage_tile<2>(W0 + (size_t)n0 * HID_ + kk, smem, boW ^ (16384 ^ 40960), tid, w);
      asm volatile("s_waitcnt vmcnt(6)" ::: "memory");
    } else {
      asm volatile("s_waitcnt vmcnt(0)" ::: "memory");
    }
    __builtin_amdgcn_s_barrier();
    const char* ab = smem + boA;
    const char* wb = smem + boW;
    bf16x8 af[4][2], bfv[2][2];
    #pragma unroll
    for (int mi = 0; mi < 4; ++mi)
      #pragma unroll
      for (int c = 0; c < 2; ++c) {
        int row = wm * 64 + mi * 16 + ql;
        af[mi][c] = *(const bf16x8*)(ab + row * 128 + (((c * 4 + g) ^ xr) * 16));
      }
    #pragma unroll
    for (int ni = 0; ni < 2; ++ni)
      #pragma unroll
      for (int c = 0; c < 2; ++c) {
        int row = wn * 32 + ni * 16 + ql;
        bfv[ni][c] = *(const bf16x8*)(wb + row * 128 + (((c * 4 + g) ^ xr) * 16));
      }
    __builtin_amdgcn_s_setprio(1);
    #pragma unroll
    for (int c = 0; c < 2; ++c)
      #pragma unroll
      for (int mi = 0; mi < 4; ++mi)
        #pragma unroll
        for (int ni = 0; ni < 2; ++ni)
          acc[mi][ni] = mfma16(af[mi][c], bfv[ni][c], acc[mi][ni]);
    __builtin_amdgcn_s_setprio(0);
    __builtin_amdgcn_s_barrier();
  }

  #pragma unroll
  for (int ni = 0; ni < 2; ++ni) {
    int n = n0 + wn * 32 + ni * 16 + ql;
    float bs = bias0[n];
    #pragma unroll
    for (int mi = 0; mi < 4; ++mi)
      #pragma unroll
      for (int i = 0; i < 4; ++i) {
        int m = m0 + wm * 64 + mi * 16 + g * 4 + i;
        outp[(size_t)m * HID_ + n] = acc[mi][ni][i] + bs;
      }
  }
}

// ---------------- flash attention (R7-exact online softmax; V read DIRECT from global) -------
// V for the 8 bh sharing an XCD = 2MB -> L2-resident; Vt rows give the PV A-fragment as a
// contiguous 16B load, so V staging is pure overhead (common-mistake #7). K staging unchanged.
__global__ __launch_bounds__(256, 4) void attn(const u16* __restrict__ Qp, const u16* __restrict__ KKp,
                                               const u16* __restrict__ Vt, const int* __restrict__ mask,
                                               u16* __restrict__ hidden) {
  __shared__ __align__(16) char smem[24576];   // K buf0@0 (8KB), K buf1@8192, P@16384 (4w x 2KB)
  const int tid = threadIdx.x;
  const int lane = tid & 63, w = tid >> 6;
  const int g = lane >> 4, ql = lane & 15;
  const int bid = blockIdx.x;
  const int bh = (bid & 7) * 8 + ((bid >> 3) & 7);
  const int qt = bid >> 6;
  const int b = bh >> 4, h = bh & 15;
  const int q0 = qt * 64;
  const int xr = ql & 7;

  // stage K iter 0 into buf0 (2 gloads)
  #pragma unroll
  for (int is = 0; is < 2; ++is) {
    int o = is * 4096 + tid * 16;
    int row = o >> 7, ch = (o >> 4) & 7;
    gload16(KKp + (size_t)(b * S_ + row) * HID_ + h * DH_ + ((ch ^ (row & 7)) * 8),
            smem + is * 4096 + w * 1024);
  }

  const u16* qrow = Qp + (size_t)(b * S_ + q0 + w * 16 + ql) * HID_ + h * DH_;
  bf16x8 qb0 = *(const bf16x8*)(qrow + g * 8);
  bf16x8 qb1 = *(const bf16x8*)(qrow + 32 + g * 8);
  const int* maskp = mask + b * S_;

  f32x4 oacc[4];
  #pragma unroll
  for (int d = 0; d < 4; ++d) oacc[d] = f32x4{0.f, 0.f, 0.f, 0.f};
  float m_run = -1e30f, l_run = 0.f;
  char* pbase = smem + 16384 + w * 2048 + ql * 128;

  int pb = 0;
  #pragma unroll 1
  for (int it = 0; it < 16; ++it) {
    const int k0 = it * 64;
    int4 mv[4];
    #pragma unroll
    for (int t = 0; t < 4; ++t) mv[t] = *(const int4*)(maskp + k0 + 16 * t + 4 * g);
    __builtin_amdgcn_sched_barrier(0);
    if (it < 15) {
      const int k0s = k0 + 64;
      const int bo = (pb ^ 1) * 8192;
      #pragma unroll
      for (int is = 0; is < 2; ++is) {
        int o = is * 4096 + tid * 16;
        int row = o >> 7, ch = (o >> 4) & 7;
        gload16(KKp + (size_t)(b * S_ + k0s + row) * HID_ + h * DH_ + ((ch ^ (row & 7)) * 8),
                smem + bo + is * 4096 + w * 1024);
      }
      asm volatile("s_waitcnt vmcnt(2)" ::: "memory");
    } else {
      asm volatile("s_waitcnt vmcnt(0)" ::: "memory");
    }
    __builtin_amdgcn_s_barrier();

    const char* kb_ = smem + pb * 8192;

    float sv[4][4];
    #pragma unroll
    for (int t = 0; t < 4; ++t) {
      const char* krow = kb_ + (16 * t + ql) * 128;
      bf16x8 ka0 = *(const bf16x8*)(krow + ((g ^ xr) * 16));
      bf16x8 ka1 = *(const bf16x8*)(krow + (((4 + g) ^ xr) * 16));
      f32x4 st = mfma16(ka0, qb0, f32x4{0.f, 0.f, 0.f, 0.f});
      st = mfma16(ka1, qb1, st);
      sv[t][0] = mv[t].x ? st[0] : -1e9f;
      sv[t][1] = mv[t].y ? st[1] : -1e9f;
      sv[t][2] = mv[t].z ? st[2] : -1e9f;
      sv[t][3] = mv[t].w ? st[3] : -1e9f;
    }
    float mloc = sv[0][0];
    #pragma unroll
    for (int t = 0; t < 4; ++t)
      #pragma unroll
      for (int i = 0; i < 4; ++i) mloc = fmaxf(mloc, sv[t][i]);
    mloc = fmaxf(mloc, __shfl_xor(mloc, 16, 64));
    mloc = fmaxf(mloc, __shfl_xor(mloc, 32, 64));
    if (__any(mloc > m_run + 10.f)) {
      float mnew = fmaxf(m_run, mloc);
      float alpha = __builtin_amdgcn_exp2f(m_run - mnew);
      l_run *= alpha;
      #pragma unroll
      for (int d = 0; d < 4; ++d) oacc[d] *= alpha;
      m_run = mnew;
    }
    float rsum = 0.f;
    float pvs[4][4];
    #pragma unroll
    for (int t = 0; t < 4; ++t)
      #pragma unroll
      for (int i = 0; i < 4; ++i) {
        float p = __builtin_amdgcn_exp2f(sv[t][i] - m_run);
        pvs[t][i] = p; rsum += p;
      }
    rsum += __shfl_xor(rsum, 16, 64);
    rsum += __shfl_xor(rsum, 32, 64);
    l_run += rsum;

    #pragma unroll
    for (int t = 0; t < 4; ++t) {
      uint2 pw;
      pw.x = cvtpk(pvs[t][0], pvs[t][1]);
      pw.y = cvtpk(pvs[t][2], pvs[t][3]);
      *(uint2*)(pbase + (((4 * t + g) ^ (2 * xr)) * 8)) = pw;
    }
    #pragma unroll
    for (int c = 0; c < 2; ++c) {
      bf16x8 pf = *(const bf16x8*)(pbase + (((c * 4 + g) ^ xr) * 16));
      #pragma unroll
      for (int d = 0; d < 4; ++d) {
        bf16x8 va = *(const bf16x8*)(Vt + (((size_t)(bh * DH_ + 16 * d + ql)) << 10)
                                        + (k0 + 32 * c + 8 * g));
        oacc[d] = mfma16(va, pf, oacc[d]);
      }
    }
    __builtin_amdgcn_s_barrier();
    pb ^= 1;
  }

  float inv = 1.0f / l_run;
  char* ep = smem + w * 2304;
  #pragma unroll
  for (int d = 0; d < 4; ++d)
    #pragma unroll
    for (int i = 0; i < 4; ++i)
      *(u16*)(ep + ql * 144 + (16 * d + 4 * g + i) * 2) = f2bf(oacc[d][i] * inv);
  __syncthreads();
  int r = lane >> 2, cc = lane & 3;
  const char* erow = smem + w * 2304 + r * 144 + cc * 32;
  uint4 v0 = *(const uint4*)erow;
  uint4 v1 = *(const uint4*)(erow + 16);
  u16* orow = hidden + (size_t)(b * S_ + q0 + w * 16 + r) * HID_ + h * DH_ + cc * 16;
  *(uint4*)orow = v0;
  *(uint4*)(orow + 8) = v1;
}

// ---------------- launch ----------------
extern "C" void kernel_launch(void* const* d_in, const int* in_sizes, int n_in,
                              void* d_out, int out_size, void* d_ws, size_t ws_size,
                              hipStream_t stream) {
  (void)in_sizes; (void)n_in; (void)out_size; (void)ws_size;
  const float* q    = (const float*)d_in[0];
  const float* k    = (const float*)d_in[1];
  const float* v    = (const float*)d_in[2];
  const float* kb   = (const float*)d_in[3];
  const int*   mask = (const int*)  d_in[4];
  const float* Wq   = (const float*)d_in[5];
  const float* bq   = (const float*)d_in[6];
  const float* Wk   = (const float*)d_in[7];
  const float* bk   = (const float*)d_in[8];
  const float* Wv   = (const float*)d_in[9];
  const float* bv   = (const float*)d_in[10];
  const float* Wkb  = (const float*)d_in[11];
  const float* bkb  = (const float*)d_in[12];
  const float* Wo   = (const float*)d_in[13];
  const float* bo   = (const float*)d_in[14];

  char* ws = (char*)d_ws;
  const size_t MB = 1024 * 1024;
  u16* qbf   = (u16*)(ws + 0 * MB);
  u16* kbf   = (u16*)(ws + 8 * MB);
  u16* vbf   = (u16*)(ws + 16 * MB);
  u16* kbbf  = (u16*)(ws + 24 * MB);
  u16* Wqbf  = (u16*)(ws + 32 * MB);
  u16* Wkbf  = (u16*)(ws + 34 * MB);
  u16* Wvbf  = (u16*)(ws + 36 * MB);
  u16* Wkbbf = (u16*)(ws + 38 * MB);
  u16* Wobf  = (u16*)(ws + 40 * MB);
  u16* Qp    = (u16*)(ws + 42 * MB);
  u16* KKp   = (u16*)(ws + 50 * MB);
  u16* Vtp   = (u16*)(ws + 58 * MB);
  u16* hid   = (u16*)(ws + 66 * MB);

  cvt_all<<<10752, 256, 0, stream>>>(q, k, v, kb, Wq, Wk, Wv, Wkb, Wo,
                                     qbf, kbf, vbf, kbbf, Wqbf, Wkbf, Wvbf, Wkbbf, Wobf);
  gemm_proj<<<1536, 256, 0, stream>>>(qbf, Wqbf, kbf, Wkbf, kbbf, Wkbbf, vbf, Wvbf,
                                      bq, bk, bkb, bv, Qp, KKp, Vtp);
  attn<<<1024, 256, 0, stream>>>(Qp, KKp, Vtp, mask, hid);
  gemm_o<<<512, 256, 0, stream>>>(hid, Wobf, bo, (float*)d_out);
}

// Round 12
// 120.476 us; speedup vs baseline: 1.2721x; 1.2721x over previous
//
#include <hip/hip_runtime.h>
#include <hip/hip_bf16.h>
#include <stdint.h>

#define B_   4
#define S_   1024
#define HID_ 1024
#define H_   16
#define DH_  64

typedef short bf16x8 __attribute__((ext_vector_type(8)));
typedef float f32x4  __attribute__((ext_vector_type(4)));
typedef unsigned int u32;
typedef unsigned short u16;

typedef u32 __attribute__((address_space(1))) as1_u32;
typedef u32 __attribute__((address_space(3))) as3_u32;

__device__ __forceinline__ f32x4 mfma16(bf16x8 a, bf16x8 b, f32x4 c) {
  return __builtin_amdgcn_mfma_f32_16x16x32_bf16(a, b, c, 0, 0, 0);
}

__device__ __forceinline__ void gload16(const void* g, void* l) {
  __builtin_amdgcn_global_load_lds((const as1_u32*)g, (as3_u32*)l, 16, 0, 0);
}

__device__ __forceinline__ u16 f2bf(float f) {
  __hip_bfloat16 h = __float2bfloat16(f);
  union { __hip_bfloat16 h; u16 u; } cv; cv.h = h; return cv.u;
}

__device__ __forceinline__ u32 cvtpk(float lo, float hi) {
  u32 r;
  asm("v_cvt_pk_bf16_f32 %0, %1, %2" : "=v"(r) : "v"(lo), "v"(hi));
  return r;
}

// stage a [NC*32 x 64] bf16 tile into LDS at byte offset bo (XOR-swizzled source)
template<int NC>
__device__ __forceinline__ void stage_tile(const u16* __restrict__ src, char* smem, int bo,
                                           int tid, int w) {
  #pragma unroll
  for (int is = 0; is < NC; ++is) {
    int o = is * 4096 + tid * 16;
    int row = o >> 7, ch = (o >> 4) & 7;
    gload16(src + (size_t)row * HID_ + ((ch ^ (row & 7)) * 8),
            smem + bo + is * 4096 + w * 1024);
  }
}

// ---------------- converts ----------------
__global__ __launch_bounds__(256) void cvt_all(
    const float* a0, const float* a1, const float* a2, const float* a3,
    const float* w0, const float* w1, const float* w2, const float* w3, const float* w4,
    u16* da0, u16* da1, u16* da2, u16* da3,
    u16* dw0, u16* dw1, u16* dw2, u16* dw3, u16* dw4) {
  int bb = blockIdx.x;
  const float* s; u16* d; size_t i;
  if (bb < 8192) {
    int t = bb * 256 + threadIdx.x;
    int sel = t >> 19;
    i = (size_t)(t & 524287) * 8;
    if (sel == 0)      { s = a0; d = da0; }
    else if (sel == 1) { s = a1; d = da1; }
    else if (sel == 2) { s = a2; d = da2; }
    else               { s = a3; d = da3; }
  } else {
    int t = (bb - 8192) * 256 + threadIdx.x;
    int sel = t >> 17;
    i = (size_t)(t & 131071) * 8;
    if (sel == 0)      { s = w0; d = dw0; }
    else if (sel == 1) { s = w1; d = dw1; }
    else if (sel == 2) { s = w2; d = dw2; }
    else if (sel == 3) { s = w3; d = dw3; }
    else               { s = w4; d = dw4; }
  }
  float4 v0 = *(const float4*)(s + i);
  float4 v1 = *(const float4*)(s + i + 4);
  uint4 r;
  r.x = cvtpk(v0.x, v0.y);
  r.y = cvtpk(v0.z, v0.w);
  r.z = cvtpk(v1.x, v1.y);
  r.w = cvtpk(v1.z, v1.w);
  *(uint4*)(d + i) = r;
}

// ---------------- fused projection GEMM: uniform 128x64 tiles, 48KB dbuf, 3 blocks/CU ----------
__global__ __launch_bounds__(256, 3) void gemm_proj(
    const u16* __restrict__ qbf, const u16* __restrict__ Wqbf,
    const u16* __restrict__ kbf, const u16* __restrict__ Wkbf,
    const u16* __restrict__ kbbf, const u16* __restrict__ Wkbbf,
    const u16* __restrict__ vbf, const u16* __restrict__ Wvbf,
    const float* __restrict__ bq, const float* __restrict__ bk,
    const float* __restrict__ bkb, const float* __restrict__ bv,
    u16* __restrict__ Qp, u16* __restrict__ KKp, u16* __restrict__ Vtp) {
  __shared__ __align__(16) char smem[49152];
  const int tid = threadIdx.x;
  const int lane = tid & 63, w = tid >> 6;
  const int g = lane >> 4, ql = lane & 15;
  const int wm = w >> 1, wn = w & 1;
  const int xr = ql & 7;
  const int xcd = blockIdx.x & 7, idx = blockIdx.x >> 3;
  const int unit = (idx < 64) ? 0 : (idx < 128) ? 1 : 2;   // 0 KK, 1 Q, 2 V
  const int id = xcd * 64 + (idx & 63);
  const int m0 = (id >> 4) * 128;
  const int n0 = (id & 15) * 64;

  const u16 *A0, *W0, *A1, *W1;
  int nkt;
  if (unit == 0)      { A0 = kbf; W0 = Wkbf; A1 = kbbf; W1 = Wkbbf; nkt = 32; }
  else if (unit == 1) { A0 = qbf; W0 = Wqbf; A1 = qbf;  W1 = Wqbf;  nkt = 16; }
  else                { A0 = vbf; W0 = Wvbf; A1 = vbf;  W1 = Wvbf;  nkt = 16; }

  f32x4 acc[4][2];
  #pragma unroll
  for (int mi = 0; mi < 4; ++mi)
    #pragma unroll
    for (int ni = 0; ni < 2; ++ni) acc[mi][ni] = f32x4{0.f, 0.f, 0.f, 0.f};

  stage_tile<4>(A0 + (size_t)m0 * HID_, smem, 0, tid, w);
  stage_tile<2>(W0 + (size_t)n0 * HID_, smem, 16384, tid, w);

  #pragma unroll 1
  for (int kt = 0; kt < nkt; ++kt) {
    const int boA = (kt & 1) ? 24576 : 0;
    const int boW = (kt & 1) ? 40960 : 16384;
    if (kt < nkt - 1) {
      int kn = kt + 1;
      const u16* As = (kn < 16) ? A0 : A1;
      const u16* Ws = (kn < 16) ? W0 : W1;
      int kk = (kn & 15) * 64;
      stage_tile<4>(As + (size_t)m0 * HID_ + kk, smem, boA ^ 24576, tid, w);
      stage_tile<2>(Ws + (size_t)n0 * HID_ + kk, smem, boW ^ (16384 ^ 40960), tid, w);
      asm volatile("s_waitcnt vmcnt(6)" ::: "memory");
    } else {
      asm volatile("s_waitcnt vmcnt(0)" ::: "memory");
    }
    __builtin_amdgcn_s_barrier();
    const char* ab = smem + boA;
    const char* wb = smem + boW;
    bf16x8 af[4][2], bfv[2][2];
    #pragma unroll
    for (int mi = 0; mi < 4; ++mi)
      #pragma unroll
      for (int c = 0; c < 2; ++c) {
        int row = wm * 64 + mi * 16 + ql;
        af[mi][c] = *(const bf16x8*)(ab + row * 128 + (((c * 4 + g) ^ xr) * 16));
      }
    #pragma unroll
    for (int ni = 0; ni < 2; ++ni)
      #pragma unroll
      for (int c = 0; c < 2; ++c) {
        int row = wn * 32 + ni * 16 + ql;
        bfv[ni][c] = *(const bf16x8*)(wb + row * 128 + (((c * 4 + g) ^ xr) * 16));
      }
    __builtin_amdgcn_s_setprio(1);
    #pragma unroll
    for (int c = 0; c < 2; ++c)
      #pragma unroll
      for (int mi = 0; mi < 4; ++mi)
        #pragma unroll
        for (int ni = 0; ni < 2; ++ni)
          acc[mi][ni] = mfma16(af[mi][c], bfv[ni][c], acc[mi][ni]);
    __builtin_amdgcn_s_setprio(0);
    __builtin_amdgcn_s_barrier();
  }

  if (unit != 2) {
    u16* outp = (unit == 0) ? KKp : Qp;
    const float osc = (unit == 1) ? 0.07216878364870322f * 1.44269504088896340f : 1.f;
    #pragma unroll
    for (int ni = 0; ni < 2; ++ni) {
      int n = n0 + wn * 32 + ni * 16 + ql;
      float bs = (unit == 0) ? (bk[n] + bkb[n]) : bq[n];
      #pragma unroll
      for (int mi = 0; mi < 4; ++mi)
        #pragma unroll
        for (int i = 0; i < 4; ++i) {
          int m = m0 + wm * 64 + mi * 16 + g * 4 + i;
          outp[(size_t)m * HID_ + n] = f2bf((acc[mi][ni][i] + bs) * osc);
        }
    }
  } else {
    char* tp = smem + w * 4096;
    #pragma unroll
    for (int ni = 0; ni < 2; ++ni) {
      int n = n0 + wn * 32 + ni * 16 + ql;
      float bs = bv[n];
      #pragma unroll
      for (int mi = 0; mi < 4; ++mi)
        #pragma unroll
        for (int i = 0; i < 4; ++i) {
          int nl = ni * 16 + ql;
          int ml = mi * 16 + g * 4 + i;
          *(u16*)(tp + nl * 128 + (((ml >> 3) ^ (nl & 7)) * 16) + (ml & 7) * 2) =
              f2bf(acc[mi][ni][i] + bs);
        }
    }
    __syncthreads();
    int r = lane >> 1, half = lane & 1;
    int n = n0 + wn * 32 + r;
    int h = n >> 6, dh = n & 63;
    int b = m0 >> 10;
    int bh = b * H_ + h;
    u16* orow = Vtp + (((size_t)(bh * DH_ + dh)) << 10) + (m0 & 1023) + wm * 64 + half * 32;
    #pragma unroll
    for (int j = 0; j < 4; ++j) {
      uint4 val = *(const uint4*)(tp + r * 128 + (((half * 4 + j) ^ (r & 7)) * 16));
      *(uint4*)(orow + j * 8) = val;
    }
  }
}

// ---------------- O GEMM (128x64 tile, bf16 in, f32 out, dbuf + counted vmcnt) ----------------
__global__ __launch_bounds__(256, 3) void gemm_o(const u16* __restrict__ A0, const u16* __restrict__ W0,
                                                 const float* __restrict__ bias0, float* __restrict__ outp) {
  __shared__ __align__(16) char smem[49152];
  const int tid = threadIdx.x;
  const int lane = tid & 63, w = tid >> 6;
  const int g = lane >> 4, ql = lane & 15;
  const int wm = w >> 1, wn = w & 1;
  const int logical = (blockIdx.x & 7) * 64 + (blockIdx.x >> 3);
  const int m0 = (logical >> 4) * 128;
  const int n0 = (logical & 15) * 64;
  const int xr = ql & 7;

  f32x4 acc[4][2];
  #pragma unroll
  for (int mi = 0; mi < 4; ++mi)
    #pragma unroll
    for (int ni = 0; ni < 2; ++ni) acc[mi][ni] = f32x4{0.f, 0.f, 0.f, 0.f};

  stage_tile<4>(A0 + (size_t)m0 * HID_, smem, 0, tid, w);
  stage_tile<2>(W0 + (size_t)n0 * HID_, smem, 16384, tid, w);

  #pragma unroll 1
  for (int kt = 0; kt < 16; ++kt) {
    const int boA = (kt & 1) ? 24576 : 0;
    const int boW = (kt & 1) ? 40960 : 16384;
    if (kt < 15) {
      int kk = (kt + 1) * 64;
      stage_tile<4>(A0 + (size_t)m0 * HID_ + kk, smem, boA ^ 24576, tid, w);
      stage_tile<2>(W0 + (size_t)n0 * HID_ + kk, smem, boW ^ (16384 ^ 40960), tid, w);
      asm volatile("s_waitcnt vmcnt(6)" ::: "memory");
    } else {
      asm volatile("s_waitcnt vmcnt(0)" ::: "memory");
    }
    __builtin_amdgcn_s_barrier();
    const char* ab = smem + boA;
    const char* wb = smem + boW;
    bf16x8 af[4][2], bfv[2][2];
    #pragma unroll
    for (int mi = 0; mi < 4; ++mi)
      #pragma unroll
      for (int c = 0; c < 2; ++c) {
        int row = wm * 64 + mi * 16 + ql;
        af[mi][c] = *(const bf16x8*)(ab + row * 128 + (((c * 4 + g) ^ xr) * 16));
      }
    #pragma unroll
    for (int ni = 0; ni < 2; ++ni)
      #pragma unroll
      for (int c = 0; c < 2; ++c) {
        int row = wn * 32 + ni * 16 + ql;
        bfv[ni][c] = *(const bf16x8*)(wb + row * 128 + (((c * 4 + g) ^ xr) * 16));
      }
    __builtin_amdgcn_s_setprio(1);
    #pragma unroll
    for (int c = 0; c < 2; ++c)
      #pragma unroll
      for (int mi = 0; mi < 4; ++mi)
        #pragma unroll
        for (int ni = 0; ni < 2; ++ni)
          acc[mi][ni] = mfma16(af[mi][c], bfv[ni][c], acc[mi][ni]);
    __builtin_amdgcn_s_setprio(0);
    __builtin_amdgcn_s_barrier();
  }

  #pragma unroll
  for (int ni = 0; ni < 2; ++ni) {
    int n = n0 + wn * 32 + ni * 16 + ql;
    float bs = bias0[n];
    #pragma unroll
    for (int mi = 0; mi < 4; ++mi)
      #pragma unroll
      for (int i = 0; i < 4; ++i) {
        int m = m0 + wm * 64 + mi * 16 + g * 4 + i;
        outp[(size_t)m * HID_ + n] = acc[mi][ni][i] + bs;
      }
  }
}

// ---------------- flash attention: R7-exact (online softmax, staged K+V, counted vmcnt) ------
// PROVEN skeleton — passed R5/R6/R7/R11-class runs. Do not restructure softmax or sync:
// fixed-shift variants (R8-R10) and V-direct (R11) all failed/regressed.
__global__ __launch_bounds__(256, 4) void attn(const u16* __restrict__ Qp, const u16* __restrict__ KKp,
                                               const u16* __restrict__ Vt, const int* __restrict__ mask,
                                               u16* __restrict__ hidden) {
  __shared__ __align__(16) char smem[40960];   // buf0 K@0 V@8192; buf1 K@16384 V@24576; P@32768
  const int tid = threadIdx.x;
  const int lane = tid & 63, w = tid >> 6;
  const int g = lane >> 4, ql = lane & 15;
  const int bid = blockIdx.x;
  const int bh = (bid & 7) * 8 + ((bid >> 3) & 7);
  const int qt = bid >> 6;
  const int b = bh >> 4, h = bh & 15;
  const int q0 = qt * 64;
  const int xr = ql & 7;

  #pragma unroll
  for (int is = 0; is < 2; ++is) {
    int o = is * 4096 + tid * 16;
    int row = o >> 7, ch = (o >> 4) & 7;
    gload16(KKp + (size_t)(b * S_ + row) * HID_ + h * DH_ + ((ch ^ (row & 7)) * 8),
            smem + is * 4096 + w * 1024);
    gload16(Vt + (size_t)(bh * DH_ + row) * S_ + ((ch ^ (row & 7)) * 8),
            smem + 8192 + is * 4096 + w * 1024);
  }

  const u16* qrow = Qp + (size_t)(b * S_ + q0 + w * 16 + ql) * HID_ + h * DH_;
  bf16x8 qb0 = *(const bf16x8*)(qrow + g * 8);
  bf16x8 qb1 = *(const bf16x8*)(qrow + 32 + g * 8);
  const int* maskp = mask + b * S_;

  f32x4 oacc[4];
  #pragma unroll
  for (int d = 0; d < 4; ++d) oacc[d] = f32x4{0.f, 0.f, 0.f, 0.f};
  float m_run = -1e30f, l_run = 0.f;
  char* pbase = smem + 32768 + w * 2048 + ql * 128;

  int pb = 0;
  #pragma unroll 1
  for (int it = 0; it < 16; ++it) {
    const int k0 = it * 64;
    int4 mv[4];
    #pragma unroll
    for (int t = 0; t < 4; ++t) mv[t] = *(const int4*)(maskp + k0 + 16 * t + 4 * g);
    __builtin_amdgcn_sched_barrier(0);
    if (it < 15) {
      const int k0s = k0 + 64;
      const int bo = (pb ^ 1) * 16384;
      #pragma unroll
      for (int is = 0; is < 2; ++is) {
        int o = is * 4096 + tid * 16;
        int row = o >> 7, ch = (o >> 4) & 7;
        gload16(KKp + (size_t)(b * S_ + k0s + row) * HID_ + h * DH_ + ((ch ^ (row & 7)) * 8),
                smem + bo + is * 4096 + w * 1024);
        gload16(Vt + (size_t)(bh * DH_ + row) * S_ + k0s + ((ch ^ (row & 7)) * 8),
                smem + bo + 8192 + is * 4096 + w * 1024);
      }
      asm volatile("s_waitcnt vmcnt(4)" ::: "memory");
    } else {
      asm volatile("s_waitcnt vmcnt(0)" ::: "memory");
    }
    __builtin_amdgcn_s_barrier();

    const char* kb_ = smem + pb * 16384;
    const char* vb_ = smem + pb * 16384 + 8192;

    float sv[4][4];
    #pragma unroll
    for (int t = 0; t < 4; ++t) {
      const char* krow = kb_ + (16 * t + ql) * 128;
      bf16x8 ka0 = *(const bf16x8*)(krow + ((g ^ xr) * 16));
      bf16x8 ka1 = *(const bf16x8*)(krow + (((4 + g) ^ xr) * 16));
      f32x4 st = mfma16(ka0, qb0, f32x4{0.f, 0.f, 0.f, 0.f});
      st = mfma16(ka1, qb1, st);
      sv[t][0] = mv[t].x ? st[0] : -1e9f;
      sv[t][1] = mv[t].y ? st[1] : -1e9f;
      sv[t][2] = mv[t].z ? st[2] : -1e9f;
      sv[t][3] = mv[t].w ? st[3] : -1e9f;
    }
    float mloc = sv[0][0];
    #pragma unroll
    for (int t = 0; t < 4; ++t)
      #pragma unroll
      for (int i = 0; i < 4; ++i) mloc = fmaxf(mloc, sv[t][i]);
    mloc = fmaxf(mloc, __shfl_xor(mloc, 16, 64));
    mloc = fmaxf(mloc, __shfl_xor(mloc, 32, 64));
    if (__any(mloc > m_run + 10.f)) {
      float mnew = fmaxf(m_run, mloc);
      float alpha = __builtin_amdgcn_exp2f(m_run - mnew);
      l_run *= alpha;
      #pragma unroll
      for (int d = 0; d < 4; ++d) oacc[d] *= alpha;
      m_run = mnew;
    }
    float rsum = 0.f;
    float pvs[4][4];
    #pragma unroll
    for (int t = 0; t < 4; ++t)
      #pragma unroll
      for (int i = 0; i < 4; ++i) {
        float p = __builtin_amdgcn_exp2f(sv[t][i] - m_run);
        pvs[t][i] = p; rsum += p;
      }
    rsum += __shfl_xor(rsum, 16, 64);
    rsum += __shfl_xor(rsum, 32, 64);
    l_run += rsum;

    #pragma unroll
    for (int t = 0; t < 4; ++t) {
      uint2 pw;
      pw.x = cvtpk(pvs[t][0], pvs[t][1]);
      pw.y = cvtpk(pvs[t][2], pvs[t][3]);
      *(uint2*)(pbase + (((4 * t + g) ^ (2 * xr)) * 8)) = pw;
    }
    #pragma unroll
    for (int c = 0; c < 2; ++c) {
      bf16x8 pf = *(const bf16x8*)(pbase + (((c * 4 + g) ^ xr) * 16));
      #pragma unroll
      for (int d = 0; d < 4; ++d) {
        bf16x8 va = *(const bf16x8*)(vb_ + (16 * d + ql) * 128 + (((c * 4 + g) ^ xr) * 16));
        oacc[d] = mfma16(va, pf, oacc[d]);
      }
    }
    __builtin_amdgcn_s_barrier();
    pb ^= 1;
  }

  float inv = 1.0f / l_run;
  char* ep = smem + w * 2304;
  #pragma unroll
  for (int d = 0; d < 4; ++d)
    #pragma unroll
    for (int i = 0; i < 4; ++i)
      *(u16*)(ep + ql * 144 + (16 * d + 4 * g + i) * 2) = f2bf(oacc[d][i] * inv);
  __syncthreads();
  int r = lane >> 2, cc = lane & 3;
  const char* erow = smem + w * 2304 + r * 144 + cc * 32;
  uint4 v0 = *(const uint4*)erow;
  uint4 v1 = *(const uint4*)(erow + 16);
  u16* orow = hidden + (size_t)(b * S_ + q0 + w * 16 + r) * HID_ + h * DH_ + cc * 16;
  *(uint4*)orow = v0;
  *(uint4*)(orow + 8) = v1;
}

// ---------------- launch ----------------
extern "C" void kernel_launch(void* const* d_in, const int* in_sizes, int n_in,
                              void* d_out, int out_size, void* d_ws, size_t ws_size,
                              hipStream_t stream) {
  (void)in_sizes; (void)n_in; (void)out_size; (void)ws_size;
  const float* q    = (const float*)d_in[0];
  const float* k    = (const float*)d_in[1];
  const float* v    = (const float*)d_in[2];
  const float* kb   = (const float*)d_in[3];
  const int*   mask = (const int*)  d_in[4];
  const float* Wq   = (const float*)d_in[5];
  const float* bq   = (const float*)d_in[6];
  const float* Wk   = (const float*)d_in[7];
  const float* bk   = (const float*)d_in[8];
  const float* Wv   = (const float*)d_in[9];
  const float* bv   = (const float*)d_in[10];
  const float* Wkb  = (const float*)d_in[11];
  const float* bkb  = (const float*)d_in[12];
  const float* Wo   = (const float*)d_in[13];
  const float* bo   = (const float*)d_in[14];

  char* ws = (char*)d_ws;
  const size_t MB = 1024 * 1024;
  u16* qbf   = (u16*)(ws + 0 * MB);
  u16* kbf   = (u16*)(ws + 8 * MB);
  u16* vbf   = (u16*)(ws + 16 * MB);
  u16* kbbf  = (u16*)(ws + 24 * MB);
  u16* Wqbf  = (u16*)(ws + 32 * MB);
  u16* Wkbf  = (u16*)(ws + 34 * MB);
  u16* Wvbf  = (u16*)(ws + 36 * MB);
  u16* Wkbbf = (u16*)(ws + 38 * MB);
  u16* Wobf  = (u16*)(ws + 40 * MB);
  u16* Qp    = (u16*)(ws + 42 * MB);
  u16* KKp   = (u16*)(ws + 50 * MB);
  u16* Vtp   = (u16*)(ws + 58 * MB);
  u16* hid   = (u16*)(ws + 66 * MB);

  cvt_all<<<10752, 256, 0, stream>>>(q, k, v, kb, Wq, Wk, Wv, Wkb, Wo,
                                     qbf, kbf, vbf, kbbf, Wqbf, Wkbf, Wvbf, Wkbbf, Wobf);
  gemm_proj<<<1536, 256, 0, stream>>>(qbf, Wqbf, kbf, Wkbf, kbbf, Wkbbf, vbf, Wvbf,
                                      bq, bk, bkb, bv, Qp, KKp, Vtp);
  attn<<<1024, 256, 0, stream>>>(Qp, KKp, Vtp, mask, hid);
  gemm_o<<<512, 256, 0, stream>>>(hid, Wobf, bo, (float*)d_out);
}

// Round 13
// 116.991 us; speedup vs baseline: 1.3100x; 1.0298x over previous
//
#include <hip/hip_runtime.h>
#include <hip/hip_bf16.h>
#include <stdint.h>

#define B_   4
#define S_   1024
#define HID_ 1024
#define H_   16
#define DH_  64

typedef short bf16x8 __attribute__((ext_vector_type(8)));
typedef float f32x4  __attribute__((ext_vector_type(4)));
typedef unsigned int u32;
typedef unsigned short u16;

typedef u32 __attribute__((address_space(1))) as1_u32;
typedef u32 __attribute__((address_space(3))) as3_u32;

__device__ __forceinline__ f32x4 mfma16(bf16x8 a, bf16x8 b, f32x4 c) {
  return __builtin_amdgcn_mfma_f32_16x16x32_bf16(a, b, c, 0, 0, 0);
}

__device__ __forceinline__ void gload16(const void* g, void* l) {
  __builtin_amdgcn_global_load_lds((const as1_u32*)g, (as3_u32*)l, 16, 0, 0);
}

__device__ __forceinline__ u16 f2bf(float f) {
  __hip_bfloat16 h = __float2bfloat16(f);
  union { __hip_bfloat16 h; u16 u; } cv; cv.h = h; return cv.u;
}

__device__ __forceinline__ u32 cvtpk(float lo, float hi) {
  u32 r;
  asm("v_cvt_pk_bf16_f32 %0, %1, %2" : "=v"(r) : "v"(lo), "v"(hi));
  return r;
}

// stage a [NC*32 x 64] bf16 tile into LDS at byte offset bo (XOR-swizzled source)
template<int NC>
__device__ __forceinline__ void stage_tile(const u16* __restrict__ src, char* smem, int bo,
                                           int tid, int w) {
  #pragma unroll
  for (int is = 0; is < NC; ++is) {
    int o = is * 4096 + tid * 16;
    int row = o >> 7, ch = (o >> 4) & 7;
    gload16(src + (size_t)row * HID_ + ((ch ^ (row & 7)) * 8),
            smem + bo + is * 4096 + w * 1024);
  }
}

// ---------------- converts ----------------
__global__ __launch_bounds__(256) void cvt_all(
    const float* a0, const float* a1, const float* a2, const float* a3,
    const float* w0, const float* w1, const float* w2, const float* w3, const float* w4,
    u16* da0, u16* da1, u16* da2, u16* da3,
    u16* dw0, u16* dw1, u16* dw2, u16* dw3, u16* dw4) {
  int bb = blockIdx.x;
  const float* s; u16* d; size_t i;
  if (bb < 8192) {
    int t = bb * 256 + threadIdx.x;
    int sel = t >> 19;
    i = (size_t)(t & 524287) * 8;
    if (sel == 0)      { s = a0; d = da0; }
    else if (sel == 1) { s = a1; d = da1; }
    else if (sel == 2) { s = a2; d = da2; }
    else               { s = a3; d = da3; }
  } else {
    int t = (bb - 8192) * 256 + threadIdx.x;
    int sel = t >> 17;
    i = (size_t)(t & 131071) * 8;
    if (sel == 0)      { s = w0; d = dw0; }
    else if (sel == 1) { s = w1; d = dw1; }
    else if (sel == 2) { s = w2; d = dw2; }
    else if (sel == 3) { s = w3; d = dw3; }
    else               { s = w4; d = dw4; }
  }
  float4 v0 = *(const float4*)(s + i);
  float4 v1 = *(const float4*)(s + i + 4);
  uint4 r;
  r.x = cvtpk(v0.x, v0.y);
  r.y = cvtpk(v0.z, v0.w);
  r.z = cvtpk(v1.x, v1.y);
  r.w = cvtpk(v1.z, v1.w);
  *(uint4*)(d + i) = r;
}

// ---------------- fused projection GEMM: uniform 128x64 tiles, 48KB dbuf, 3 blocks/CU ----------
__global__ __launch_bounds__(256, 3) void gemm_proj(
    const u16* __restrict__ qbf, const u16* __restrict__ Wqbf,
    const u16* __restrict__ kbf, const u16* __restrict__ Wkbf,
    const u16* __restrict__ kbbf, const u16* __restrict__ Wkbbf,
    const u16* __restrict__ vbf, const u16* __restrict__ Wvbf,
    const float* __restrict__ bq, const float* __restrict__ bk,
    const float* __restrict__ bkb, const float* __restrict__ bv,
    u16* __restrict__ Qp, u16* __restrict__ KKp, u16* __restrict__ Vtp) {
  __shared__ __align__(16) char smem[49152];
  const int tid = threadIdx.x;
  const int lane = tid & 63, w = tid >> 6;
  const int g = lane >> 4, ql = lane & 15;
  const int wm = w >> 1, wn = w & 1;
  const int xr = ql & 7;
  const int xcd = blockIdx.x & 7, idx = blockIdx.x >> 3;
  const int unit = (idx < 64) ? 0 : (idx < 128) ? 1 : 2;   // 0 KK, 1 Q, 2 V
  const int id = xcd * 64 + (idx & 63);
  const int m0 = (id >> 4) * 128;
  const int n0 = (id & 15) * 64;

  const u16 *A0, *W0, *A1, *W1;
  int nkt;
  if (unit == 0)      { A0 = kbf; W0 = Wkbf; A1 = kbbf; W1 = Wkbbf; nkt = 32; }
  else if (unit == 1) { A0 = qbf; W0 = Wqbf; A1 = qbf;  W1 = Wqbf;  nkt = 16; }
  else                { A0 = vbf; W0 = Wvbf; A1 = vbf;  W1 = Wvbf;  nkt = 16; }

  f32x4 acc[4][2];
  #pragma unroll
  for (int mi = 0; mi < 4; ++mi)
    #pragma unroll
    for (int ni = 0; ni < 2; ++ni) acc[mi][ni] = f32x4{0.f, 0.f, 0.f, 0.f};

  stage_tile<4>(A0 + (size_t)m0 * HID_, smem, 0, tid, w);
  stage_tile<2>(W0 + (size_t)n0 * HID_, smem, 16384, tid, w);

  #pragma unroll 1
  for (int kt = 0; kt < nkt; ++kt) {
    const int boA = (kt & 1) ? 24576 : 0;
    const int boW = (kt & 1) ? 40960 : 16384;
    if (kt < nkt - 1) {
      int kn = kt + 1;
      const u16* As = (kn < 16) ? A0 : A1;
      const u16* Ws = (kn < 16) ? W0 : W1;
      int kk = (kn & 15) * 64;
      stage_tile<4>(As + (size_t)m0 * HID_ + kk, smem, boA ^ 24576, tid, w);
      stage_tile<2>(Ws + (size_t)n0 * HID_ + kk, smem, boW ^ (16384 ^ 40960), tid, w);
      asm volatile("s_waitcnt vmcnt(6)" ::: "memory");
    } else {
      asm volatile("s_waitcnt vmcnt(0)" ::: "memory");
    }
    __builtin_amdgcn_s_barrier();
    const char* ab = smem + boA;
    const char* wb = smem + boW;
    bf16x8 af[4][2], bfv[2][2];
    #pragma unroll
    for (int mi = 0; mi < 4; ++mi)
      #pragma unroll
      for (int c = 0; c < 2; ++c) {
        int row = wm * 64 + mi * 16 + ql;
        af[mi][c] = *(const bf16x8*)(ab + row * 128 + (((c * 4 + g) ^ xr) * 16));
      }
    #pragma unroll
    for (int ni = 0; ni < 2; ++ni)
      #pragma unroll
      for (int c = 0; c < 2; ++c) {
        int row = wn * 32 + ni * 16 + ql;
        bfv[ni][c] = *(const bf16x8*)(wb + row * 128 + (((c * 4 + g) ^ xr) * 16));
      }
    __builtin_amdgcn_s_setprio(1);
    #pragma unroll
    for (int c = 0; c < 2; ++c)
      #pragma unroll
      for (int mi = 0; mi < 4; ++mi)
        #pragma unroll
        for (int ni = 0; ni < 2; ++ni)
          acc[mi][ni] = mfma16(af[mi][c], bfv[ni][c], acc[mi][ni]);
    __builtin_amdgcn_s_setprio(0);
    __builtin_amdgcn_s_barrier();
  }

  if (unit != 2) {
    u16* outp = (unit == 0) ? KKp : Qp;
    const float osc = (unit == 1) ? 0.07216878364870322f * 1.44269504088896340f : 1.f;
    #pragma unroll
    for (int ni = 0; ni < 2; ++ni) {
      int n = n0 + wn * 32 + ni * 16 + ql;
      float bs = (unit == 0) ? (bk[n] + bkb[n]) : bq[n];
      #pragma unroll
      for (int mi = 0; mi < 4; ++mi)
        #pragma unroll
        for (int i = 0; i < 4; ++i) {
          int m = m0 + wm * 64 + mi * 16 + g * 4 + i;
          outp[(size_t)m * HID_ + n] = f2bf((acc[mi][ni][i] + bs) * osc);
        }
    }
  } else {
    char* tp = smem + w * 4096;
    #pragma unroll
    for (int ni = 0; ni < 2; ++ni) {
      int n = n0 + wn * 32 + ni * 16 + ql;
      float bs = bv[n];
      #pragma unroll
      for (int mi = 0; mi < 4; ++mi)
        #pragma unroll
        for (int i = 0; i < 4; ++i) {
          int nl = ni * 16 + ql;
          int ml = mi * 16 + g * 4 + i;
          *(u16*)(tp + nl * 128 + (((ml >> 3) ^ (nl & 7)) * 16) + (ml & 7) * 2) =
              f2bf(acc[mi][ni][i] + bs);
        }
    }
    __syncthreads();
    int r = lane >> 1, half = lane & 1;
    int n = n0 + wn * 32 + r;
    int h = n >> 6, dh = n & 63;
    int b = m0 >> 10;
    int bh = b * H_ + h;
    u16* orow = Vtp + (((size_t)(bh * DH_ + dh)) << 10) + (m0 & 1023) + wm * 64 + half * 32;
    #pragma unroll
    for (int j = 0; j < 4; ++j) {
      uint4 val = *(const uint4*)(tp + r * 128 + (((half * 4 + j) ^ (r & 7)) * 16));
      *(uint4*)(orow + j * 8) = val;
    }
  }
}

// ---------------- O GEMM (128x64 tile, bf16 in, f32 out, dbuf + counted vmcnt) ----------------
__global__ __launch_bounds__(256, 3) void gemm_o(const u16* __restrict__ A0, const u16* __restrict__ W0,
                                                 const float* __restrict__ bias0, float* __restrict__ outp) {
  __shared__ __align__(16) char smem[49152];
  const int tid = threadIdx.x;
  const int lane = tid & 63, w = tid >> 6;
  const int g = lane >> 4, ql = lane & 15;
  const int wm = w >> 1, wn = w & 1;
  const int logical = (blockIdx.x & 7) * 64 + (blockIdx.x >> 3);
  const int m0 = (logical >> 4) * 128;
  const int n0 = (logical & 15) * 64;
  const int xr = ql & 7;

  f32x4 acc[4][2];
  #pragma unroll
  for (int mi = 0; mi < 4; ++mi)
    #pragma unroll
    for (int ni = 0; ni < 2; ++ni) acc[mi][ni] = f32x4{0.f, 0.f, 0.f, 0.f};

  stage_tile<4>(A0 + (size_t)m0 * HID_, smem, 0, tid, w);
  stage_tile<2>(W0 + (size_t)n0 * HID_, smem, 16384, tid, w);

  #pragma unroll 1
  for (int kt = 0; kt < 16; ++kt) {
    const int boA = (kt & 1) ? 24576 : 0;
    const int boW = (kt & 1) ? 40960 : 16384;
    if (kt < 15) {
      int kk = (kt + 1) * 64;
      stage_tile<4>(A0 + (size_t)m0 * HID_ + kk, smem, boA ^ 24576, tid, w);
      stage_tile<2>(W0 + (size_t)n0 * HID_ + kk, smem, boW ^ (16384 ^ 40960), tid, w);
      asm volatile("s_waitcnt vmcnt(6)" ::: "memory");
    } else {
      asm volatile("s_waitcnt vmcnt(0)" ::: "memory");
    }
    __builtin_amdgcn_s_barrier();
    const char* ab = smem + boA;
    const char* wb = smem + boW;
    bf16x8 af[4][2], bfv[2][2];
    #pragma unroll
    for (int mi = 0; mi < 4; ++mi)
      #pragma unroll
      for (int c = 0; c < 2; ++c) {
        int row = wm * 64 + mi * 16 + ql;
        af[mi][c] = *(const bf16x8*)(ab + row * 128 + (((c * 4 + g) ^ xr) * 16));
      }
    #pragma unroll
    for (int ni = 0; ni < 2; ++ni)
      #pragma unroll
      for (int c = 0; c < 2; ++c) {
        int row = wn * 32 + ni * 16 + ql;
        bfv[ni][c] = *(const bf16x8*)(wb + row * 128 + (((c * 4 + g) ^ xr) * 16));
      }
    __builtin_amdgcn_s_setprio(1);
    #pragma unroll
    for (int c = 0; c < 2; ++c)
      #pragma unroll
      for (int mi = 0; mi < 4; ++mi)
        #pragma unroll
        for (int ni = 0; ni < 2; ++ni)
          acc[mi][ni] = mfma16(af[mi][c], bfv[ni][c], acc[mi][ni]);
    __builtin_amdgcn_s_setprio(0);
    __builtin_amdgcn_s_barrier();
  }

  #pragma unroll
  for (int ni = 0; ni < 2; ++ni) {
    int n = n0 + wn * 32 + ni * 16 + ql;
    float bs = bias0[n];
    #pragma unroll
    for (int mi = 0; mi < 4; ++mi)
      #pragma unroll
      for (int i = 0; i < 4; ++i) {
        int m = m0 + wm * 64 + mi * 16 + g * 4 + i;
        outp[(size_t)m * HID_ + n] = acc[mi][ni][i] + bs;
      }
  }
}

// ---------------- flash attention: R7 skeleton, 8 waves/block, QBLK=128 ----------------
// Same proven loop body (online softmax, staged K+V, counted vmcnt). 512 threads cover each
// 8KB K/V tile in ONE gload per thread -> vmcnt(2). K/V staging amortized over 2x q-rows;
// 3 blocks/CU x 8 waves = 24 waves/CU.
__global__ __launch_bounds__(512, 6) void attn(const u16* __restrict__ Qp, const u16* __restrict__ KKp,
                                               const u16* __restrict__ Vt, const int* __restrict__ mask,
                                               u16* __restrict__ hidden) {
  __shared__ __align__(16) char smem[49152];   // buf0 K@0 V@8192; buf1 K@16384 V@24576; P@32768 (8x2KB)
  const int tid = threadIdx.x;
  const int lane = tid & 63, w = tid >> 6;     // w in 0..7
  const int g = lane >> 4, ql = lane & 15;
  const int bid = blockIdx.x;                  // 512 = 8 xcd x 8 bh-sub x 8 qt
  const int bh = (bid & 7) * 8 + ((bid >> 3) & 7);
  const int qt = bid >> 6;                     // 0..7
  const int b = bh >> 4, h = bh & 15;
  const int q0 = qt * 128;
  const int xr = ql & 7;

  // stage tile 0 into buf0: 512 threads cover 8KB K + 8KB V in one gload each
  {
    int o = tid * 16;
    int row = o >> 7, ch = (o >> 4) & 7;
    gload16(KKp + (size_t)(b * S_ + row) * HID_ + h * DH_ + ((ch ^ (row & 7)) * 8),
            smem + w * 1024);
    gload16(Vt + (size_t)(bh * DH_ + row) * S_ + ((ch ^ (row & 7)) * 8),
            smem + 8192 + w * 1024);
  }

  const u16* qrow = Qp + (size_t)(b * S_ + q0 + w * 16 + ql) * HID_ + h * DH_;
  bf16x8 qb0 = *(const bf16x8*)(qrow + g * 8);
  bf16x8 qb1 = *(const bf16x8*)(qrow + 32 + g * 8);
  const int* maskp = mask + b * S_;

  f32x4 oacc[4];
  #pragma unroll
  for (int d = 0; d < 4; ++d) oacc[d] = f32x4{0.f, 0.f, 0.f, 0.f};
  float m_run = -1e30f, l_run = 0.f;
  char* pbase = smem + 32768 + w * 2048 + ql * 128;

  int pb = 0;
  #pragma unroll 1
  for (int it = 0; it < 16; ++it) {
    const int k0 = it * 64;
    int4 mv[4];
    #pragma unroll
    for (int t = 0; t < 4; ++t) mv[t] = *(const int4*)(maskp + k0 + 16 * t + 4 * g);
    __builtin_amdgcn_sched_barrier(0);
    if (it < 15) {
      const int k0s = k0 + 64;
      const int bo = (pb ^ 1) * 16384;
      int o = tid * 16;
      int row = o >> 7, ch = (o >> 4) & 7;
      gload16(KKp + (size_t)(b * S_ + k0s + row) * HID_ + h * DH_ + ((ch ^ (row & 7)) * 8),
              smem + bo + w * 1024);
      gload16(Vt + (size_t)(bh * DH_ + row) * S_ + k0s + ((ch ^ (row & 7)) * 8),
              smem + bo + 8192 + w * 1024);
      asm volatile("s_waitcnt vmcnt(2)" ::: "memory");
    } else {
      asm volatile("s_waitcnt vmcnt(0)" ::: "memory");
    }
    __builtin_amdgcn_s_barrier();

    const char* kb_ = smem + pb * 16384;
    const char* vb_ = smem + pb * 16384 + 8192;

    float sv[4][4];
    #pragma unroll
    for (int t = 0; t < 4; ++t) {
      const char* krow = kb_ + (16 * t + ql) * 128;
      bf16x8 ka0 = *(const bf16x8*)(krow + ((g ^ xr) * 16));
      bf16x8 ka1 = *(const bf16x8*)(krow + (((4 + g) ^ xr) * 16));
      f32x4 st = mfma16(ka0, qb0, f32x4{0.f, 0.f, 0.f, 0.f});
      st = mfma16(ka1, qb1, st);
      sv[t][0] = mv[t].x ? st[0] : -1e9f;
      sv[t][1] = mv[t].y ? st[1] : -1e9f;
      sv[t][2] = mv[t].z ? st[2] : -1e9f;
      sv[t][3] = mv[t].w ? st[3] : -1e9f;
    }
    float mloc = sv[0][0];
    #pragma unroll
    for (int t = 0; t < 4; ++t)
      #pragma unroll
      for (int i = 0; i < 4; ++i) mloc = fmaxf(mloc, sv[t][i]);
    mloc = fmaxf(mloc, __shfl_xor(mloc, 16, 64));
    mloc = fmaxf(mloc, __shfl_xor(mloc, 32, 64));
    if (__any(mloc > m_run + 10.f)) {
      float mnew = fmaxf(m_run, mloc);
      float alpha = __builtin_amdgcn_exp2f(m_run - mnew);
      l_run *= alpha;
      #pragma unroll
      for (int d = 0; d < 4; ++d) oacc[d] *= alpha;
      m_run = mnew;
    }
    float rsum = 0.f;
    float pvs[4][4];
    #pragma unroll
    for (int t = 0; t < 4; ++t)
      #pragma unroll
      for (int i = 0; i < 4; ++i) {
        float p = __builtin_amdgcn_exp2f(sv[t][i] - m_run);
        pvs[t][i] = p; rsum += p;
      }
    rsum += __shfl_xor(rsum, 16, 64);
    rsum += __shfl_xor(rsum, 32, 64);
    l_run += rsum;

    #pragma unroll
    for (int t = 0; t < 4; ++t) {
      uint2 pw;
      pw.x = cvtpk(pvs[t][0], pvs[t][1]);
      pw.y = cvtpk(pvs[t][2], pvs[t][3]);
      *(uint2*)(pbase + (((4 * t + g) ^ (2 * xr)) * 8)) = pw;
    }
    #pragma unroll
    for (int c = 0; c < 2; ++c) {
      bf16x8 pf = *(const bf16x8*)(pbase + (((c * 4 + g) ^ xr) * 16));
      #pragma unroll
      for (int d = 0; d < 4; ++d) {
        bf16x8 va = *(const bf16x8*)(vb_ + (16 * d + ql) * 128 + (((c * 4 + g) ^ xr) * 16));
        oacc[d] = mfma16(va, pf, oacc[d]);
      }
    }
    __builtin_amdgcn_s_barrier();
    pb ^= 1;
  }

  float inv = 1.0f / l_run;
  char* ep = smem + w * 2304;
  #pragma unroll
  for (int d = 0; d < 4; ++d)
    #pragma unroll
    for (int i = 0; i < 4; ++i)
      *(u16*)(ep + ql * 144 + (16 * d + 4 * g + i) * 2) = f2bf(oacc[d][i] * inv);
  __syncthreads();
  int r = lane >> 2, cc = lane & 3;
  const char* erow = smem + w * 2304 + r * 144 + cc * 32;
  uint4 v0 = *(const uint4*)erow;
  uint4 v1 = *(const uint4*)(erow + 16);
  u16* orow = hidden + (size_t)(b * S_ + q0 + w * 16 + r) * HID_ + h * DH_ + cc * 16;
  *(uint4*)orow = v0;
  *(uint4*)(orow + 8) = v1;
}

// ---------------- launch ----------------
extern "C" void kernel_launch(void* const* d_in, const int* in_sizes, int n_in,
                              void* d_out, int out_size, void* d_ws, size_t ws_size,
                              hipStream_t stream) {
  (void)in_sizes; (void)n_in; (void)out_size; (void)ws_size;
  const float* q    = (const float*)d_in[0];
  const float* k    = (const float*)d_in[1];
  const float* v    = (const float*)d_in[2];
  const float* kb   = (const float*)d_in[3];
  const int*   mask = (const int*)  d_in[4];
  const float* Wq   = (const float*)d_in[5];
  const float* bq   = (const float*)d_in[6];
  const float* Wk   = (const float*)d_in[7];
  const float* bk   = (const float*)d_in[8];
  const float* Wv   = (const float*)d_in[9];
  const float* bv   = (const float*)d_in[10];
  const float* Wkb  = (const float*)d_in[11];
  const float* bkb  = (const float*)d_in[12];
  const float* Wo   = (const float*)d_in[13];
  const float* bo   = (const float*)d_in[14];

  char* ws = (char*)d_ws;
  const size_t MB = 1024 * 1024;
  u16* qbf   = (u16*)(ws + 0 * MB);
  u16* kbf   = (u16*)(ws + 8 * MB);
  u16* vbf   = (u16*)(ws + 16 * MB);
  u16* kbbf  = (u16*)(ws + 24 * MB);
  u16* Wqbf  = (u16*)(ws + 32 * MB);
  u16* Wkbf  = (u16*)(ws + 34 * MB);
  u16* Wvbf  = (u16*)(ws + 36 * MB);
  u16* Wkbbf = (u16*)(ws + 38 * MB);
  u16* Wobf  = (u16*)(ws + 40 * MB);
  u16* Qp    = (u16*)(ws + 42 * MB);
  u16* KKp   = (u16*)(ws + 50 * MB);
  u16* Vtp   = (u16*)(ws + 58 * MB);
  u16* hid   = (u16*)(ws + 66 * MB);

  cvt_all<<<10752, 256, 0, stream>>>(q, k, v, kb, Wq, Wk, Wv, Wkb, Wo,
                                     qbf, kbf, vbf, kbbf, Wqbf, Wkbf, Wvbf, Wkbbf, Wobf);
  gemm_proj<<<1536, 256, 0, stream>>>(qbf, Wqbf, kbf, Wkbf, kbbf, Wkbbf, vbf, Wvbf,
                                      bq, bk, bkb, bv, Qp, KKp, Vtp);
  attn<<<512, 512, 0, stream>>>(Qp, KKp, Vtp, mask, hid);
  gemm_o<<<512, 256, 0, stream>>>(hid, Wobf, bo, (float*)d_out);
}

// Round 14
// 116.054 us; speedup vs baseline: 1.3205x; 1.0081x over previous
//
#include <hip/hip_runtime.h>
#include <hip/hip_bf16.h>
#include <stdint.h>

#define B_   4
#define S_   1024
#define HID_ 1024
#define H_   16
#define DH_  64

typedef short bf16x8 __attribute__((ext_vector_type(8)));
typedef float f32x4  __attribute__((ext_vector_type(4)));
typedef unsigned int u32;
typedef unsigned short u16;

typedef u32 __attribute__((address_space(1))) as1_u32;
typedef u32 __attribute__((address_space(3))) as3_u32;

__device__ __forceinline__ f32x4 mfma16(bf16x8 a, bf16x8 b, f32x4 c) {
  return __builtin_amdgcn_mfma_f32_16x16x32_bf16(a, b, c, 0, 0, 0);
}

__device__ __forceinline__ void gload16(const void* g, void* l) {
  __builtin_amdgcn_global_load_lds((const as1_u32*)g, (as3_u32*)l, 16, 0, 0);
}

__device__ __forceinline__ u16 f2bf(float f) {
  __hip_bfloat16 h = __float2bfloat16(f);
  union { __hip_bfloat16 h; u16 u; } cv; cv.h = h; return cv.u;
}

__device__ __forceinline__ u32 cvtpk(float lo, float hi) {
  u32 r;
  asm("v_cvt_pk_bf16_f32 %0, %1, %2" : "=v"(r) : "v"(lo), "v"(hi));
  return r;
}

// stage a [NC*32 x 64] bf16 tile into LDS at byte offset bo (XOR-swizzled source)
template<int NC>
__device__ __forceinline__ void stage_tile(const u16* __restrict__ src, char* smem, int bo,
                                           int tid, int w) {
  #pragma unroll
  for (int is = 0; is < NC; ++is) {
    int o = is * 4096 + tid * 16;
    int row = o >> 7, ch = (o >> 4) & 7;
    gload16(src + (size_t)row * HID_ + ((ch ^ (row & 7)) * 8),
            smem + bo + is * 4096 + w * 1024);
  }
}

// ---------------- converts ----------------
__global__ __launch_bounds__(256) void cvt_all(
    const float* a0, const float* a1, const float* a2, const float* a3,
    const float* w0, const float* w1, const float* w2, const float* w3, const float* w4,
    u16* da0, u16* da1, u16* da2, u16* da3,
    u16* dw0, u16* dw1, u16* dw2, u16* dw3, u16* dw4) {
  int bb = blockIdx.x;
  const float* s; u16* d; size_t i;
  if (bb < 8192) {
    int t = bb * 256 + threadIdx.x;
    int sel = t >> 19;
    i = (size_t)(t & 524287) * 8;
    if (sel == 0)      { s = a0; d = da0; }
    else if (sel == 1) { s = a1; d = da1; }
    else if (sel == 2) { s = a2; d = da2; }
    else               { s = a3; d = da3; }
  } else {
    int t = (bb - 8192) * 256 + threadIdx.x;
    int sel = t >> 17;
    i = (size_t)(t & 131071) * 8;
    if (sel == 0)      { s = w0; d = dw0; }
    else if (sel == 1) { s = w1; d = dw1; }
    else if (sel == 2) { s = w2; d = dw2; }
    else if (sel == 3) { s = w3; d = dw3; }
    else               { s = w4; d = dw4; }
  }
  float4 v0 = *(const float4*)(s + i);
  float4 v1 = *(const float4*)(s + i + 4);
  uint4 r;
  r.x = cvtpk(v0.x, v0.y);
  r.y = cvtpk(v0.z, v0.w);
  r.z = cvtpk(v1.x, v1.y);
  r.w = cvtpk(v1.z, v1.w);
  *(uint4*)(d + i) = r;
}

// ---------------- fused projection GEMM: uniform 128x64 tiles, 48KB dbuf, 3 blocks/CU ----------
__global__ __launch_bounds__(256, 3) void gemm_proj(
    const u16* __restrict__ qbf, const u16* __restrict__ Wqbf,
    const u16* __restrict__ kbf, const u16* __restrict__ Wkbf,
    const u16* __restrict__ kbbf, const u16* __restrict__ Wkbbf,
    const u16* __restrict__ vbf, const u16* __restrict__ Wvbf,
    const float* __restrict__ bq, const float* __restrict__ bk,
    const float* __restrict__ bkb, const float* __restrict__ bv,
    u16* __restrict__ Qp, u16* __restrict__ KKp, u16* __restrict__ Vtp) {
  __shared__ __align__(16) char smem[49152];
  const int tid = threadIdx.x;
  const int lane = tid & 63, w = tid >> 6;
  const int g = lane >> 4, ql = lane & 15;
  const int wm = w >> 1, wn = w & 1;
  const int xr = ql & 7;
  const int xcd = blockIdx.x & 7, idx = blockIdx.x >> 3;
  const int unit = (idx < 64) ? 0 : (idx < 128) ? 1 : 2;   // 0 KK, 1 Q, 2 V
  const int id = xcd * 64 + (idx & 63);
  const int m0 = (id >> 4) * 128;
  const int n0 = (id & 15) * 64;

  const u16 *A0, *W0, *A1, *W1;
  int nkt;
  if (unit == 0)      { A0 = kbf; W0 = Wkbf; A1 = kbbf; W1 = Wkbbf; nkt = 32; }
  else if (unit == 1) { A0 = qbf; W0 = Wqbf; A1 = qbf;  W1 = Wqbf;  nkt = 16; }
  else                { A0 = vbf; W0 = Wvbf; A1 = vbf;  W1 = Wvbf;  nkt = 16; }

  f32x4 acc[4][2];
  #pragma unroll
  for (int mi = 0; mi < 4; ++mi)
    #pragma unroll
    for (int ni = 0; ni < 2; ++ni) acc[mi][ni] = f32x4{0.f, 0.f, 0.f, 0.f};

  stage_tile<4>(A0 + (size_t)m0 * HID_, smem, 0, tid, w);
  stage_tile<2>(W0 + (size_t)n0 * HID_, smem, 16384, tid, w);

  #pragma unroll 1
  for (int kt = 0; kt < nkt; ++kt) {
    const int boA = (kt & 1) ? 24576 : 0;
    const int boW = (kt & 1) ? 40960 : 16384;
    if (kt < nkt - 1) {
      int kn = kt + 1;
      const u16* As = (kn < 16) ? A0 : A1;
      const u16* Ws = (kn < 16) ? W0 : W1;
      int kk = (kn & 15) * 64;
      stage_tile<4>(As + (size_t)m0 * HID_ + kk, smem, boA ^ 24576, tid, w);
      stage_tile<2>(Ws + (size_t)n0 * HID_ + kk, smem, boW ^ (16384 ^ 40960), tid, w);
      asm volatile("s_waitcnt vmcnt(6)" ::: "memory");
    } else {
      asm volatile("s_waitcnt vmcnt(0)" ::: "memory");
    }
    __builtin_amdgcn_s_barrier();
    const char* ab = smem + boA;
    const char* wb = smem + boW;
    bf16x8 af[4][2], bfv[2][2];
    #pragma unroll
    for (int mi = 0; mi < 4; ++mi)
      #pragma unroll
      for (int c = 0; c < 2; ++c) {
        int row = wm * 64 + mi * 16 + ql;
        af[mi][c] = *(const bf16x8*)(ab + row * 128 + (((c * 4 + g) ^ xr) * 16));
      }
    #pragma unroll
    for (int ni = 0; ni < 2; ++ni)
      #pragma unroll
      for (int c = 0; c < 2; ++c) {
        int row = wn * 32 + ni * 16 + ql;
        bfv[ni][c] = *(const bf16x8*)(wb + row * 128 + (((c * 4 + g) ^ xr) * 16));
      }
    __builtin_amdgcn_s_setprio(1);
    #pragma unroll
    for (int c = 0; c < 2; ++c)
      #pragma unroll
      for (int mi = 0; mi < 4; ++mi)
        #pragma unroll
        for (int ni = 0; ni < 2; ++ni)
          acc[mi][ni] = mfma16(af[mi][c], bfv[ni][c], acc[mi][ni]);
    __builtin_amdgcn_s_setprio(0);
    __builtin_amdgcn_s_barrier();
  }

  if (unit != 2) {
    u16* outp = (unit == 0) ? KKp : Qp;
    const float osc = (unit == 1) ? 0.07216878364870322f * 1.44269504088896340f : 1.f;
    #pragma unroll
    for (int ni = 0; ni < 2; ++ni) {
      int n = n0 + wn * 32 + ni * 16 + ql;
      float bs = (unit == 0) ? (bk[n] + bkb[n]) : bq[n];
      #pragma unroll
      for (int mi = 0; mi < 4; ++mi)
        #pragma unroll
        for (int i = 0; i < 4; ++i) {
          int m = m0 + wm * 64 + mi * 16 + g * 4 + i;
          outp[(size_t)m * HID_ + n] = f2bf((acc[mi][ni][i] + bs) * osc);
        }
    }
  } else {
    char* tp = smem + w * 4096;
    #pragma unroll
    for (int ni = 0; ni < 2; ++ni) {
      int n = n0 + wn * 32 + ni * 16 + ql;
      float bs = bv[n];
      #pragma unroll
      for (int mi = 0; mi < 4; ++mi)
        #pragma unroll
        for (int i = 0; i < 4; ++i) {
          int nl = ni * 16 + ql;
          int ml = mi * 16 + g * 4 + i;
          *(u16*)(tp + nl * 128 + (((ml >> 3) ^ (nl & 7)) * 16) + (ml & 7) * 2) =
              f2bf(acc[mi][ni][i] + bs);
        }
    }
    __syncthreads();
    int r = lane >> 1, half = lane & 1;
    int n = n0 + wn * 32 + r;
    int h = n >> 6, dh = n & 63;
    int b = m0 >> 10;
    int bh = b * H_ + h;
    u16* orow = Vtp + (((size_t)(bh * DH_ + dh)) << 10) + (m0 & 1023) + wm * 64 + half * 32;
    #pragma unroll
    for (int j = 0; j < 4; ++j) {
      uint4 val = *(const uint4*)(tp + r * 128 + (((half * 4 + j) ^ (r & 7)) * 16));
      *(uint4*)(orow + j * 8) = val;
    }
  }
}

// ---------------- O GEMM (128x64 tile, bf16 in, f32 out, dbuf + counted vmcnt) ----------------
__global__ __launch_bounds__(256, 3) void gemm_o(const u16* __restrict__ A0, const u16* __restrict__ W0,
                                                 const float* __restrict__ bias0, float* __restrict__ outp) {
  __shared__ __align__(16) char smem[49152];
  const int tid = threadIdx.x;
  const int lane = tid & 63, w = tid >> 6;
  const int g = lane >> 4, ql = lane & 15;
  const int wm = w >> 1, wn = w & 1;
  const int logical = (blockIdx.x & 7) * 64 + (blockIdx.x >> 3);
  const int m0 = (logical >> 4) * 128;
  const int n0 = (logical & 15) * 64;
  const int xr = ql & 7;

  f32x4 acc[4][2];
  #pragma unroll
  for (int mi = 0; mi < 4; ++mi)
    #pragma unroll
    for (int ni = 0; ni < 2; ++ni) acc[mi][ni] = f32x4{0.f, 0.f, 0.f, 0.f};

  stage_tile<4>(A0 + (size_t)m0 * HID_, smem, 0, tid, w);
  stage_tile<2>(W0 + (size_t)n0 * HID_, smem, 16384, tid, w);

  #pragma unroll 1
  for (int kt = 0; kt < 16; ++kt) {
    const int boA = (kt & 1) ? 24576 : 0;
    const int boW = (kt & 1) ? 40960 : 16384;
    if (kt < 15) {
      int kk = (kt + 1) * 64;
      stage_tile<4>(A0 + (size_t)m0 * HID_ + kk, smem, boA ^ 24576, tid, w);
      stage_tile<2>(W0 + (size_t)n0 * HID_ + kk, smem, boW ^ (16384 ^ 40960), tid, w);
      asm volatile("s_waitcnt vmcnt(6)" ::: "memory");
    } else {
      asm volatile("s_waitcnt vmcnt(0)" ::: "memory");
    }
    __builtin_amdgcn_s_barrier();
    const char* ab = smem + boA;
    const char* wb = smem + boW;
    bf16x8 af[4][2], bfv[2][2];
    #pragma unroll
    for (int mi = 0; mi < 4; ++mi)
      #pragma unroll
      for (int c = 0; c < 2; ++c) {
        int row = wm * 64 + mi * 16 + ql;
        af[mi][c] = *(const bf16x8*)(ab + row * 128 + (((c * 4 + g) ^ xr) * 16));
      }
    #pragma unroll
    for (int ni = 0; ni < 2; ++ni)
      #pragma unroll
      for (int c = 0; c < 2; ++c) {
        int row = wn * 32 + ni * 16 + ql;
        bfv[ni][c] = *(const bf16x8*)(wb + row * 128 + (((c * 4 + g) ^ xr) * 16));
      }
    __builtin_amdgcn_s_setprio(1);
    #pragma unroll
    for (int c = 0; c < 2; ++c)
      #pragma unroll
      for (int mi = 0; mi < 4; ++mi)
        #pragma unroll
        for (int ni = 0; ni < 2; ++ni)
          acc[mi][ni] = mfma16(af[mi][c], bfv[ni][c], acc[mi][ni]);
    __builtin_amdgcn_s_setprio(0);
    __builtin_amdgcn_s_barrier();
  }

  #pragma unroll
  for (int ni = 0; ni < 2; ++ni) {
    int n = n0 + wn * 32 + ni * 16 + ql;
    float bs = bias0[n];
    #pragma unroll
    for (int mi = 0; mi < 4; ++mi)
      #pragma unroll
      for (int i = 0; i < 4; ++i) {
        int m = m0 + wm * 64 + mi * 16 + g * 4 + i;
        outp[(size_t)m * HID_ + n] = acc[mi][ni][i] + bs;
      }
  }
}

// ---------------- flash attention: R13 skeleton + mask preconverted to additive f32 in LDS ----
// Mask row (4KB) converted once at entry; per-iter mask access is a broadcast LDS read, so the
// stage gloads are the only VMEM ops in the loop (vmcnt(2)/(0) accounting unchanged).
__global__ __launch_bounds__(512, 6) void attn(const u16* __restrict__ Qp, const u16* __restrict__ KKp,
                                               const u16* __restrict__ Vt, const int* __restrict__ mask,
                                               u16* __restrict__ hidden) {
  __shared__ __align__(16) char smem[53248];   // K/V dbuf 32KB; P@32768 (8x2KB); madd@49152 (4KB)
  const int tid = threadIdx.x;
  const int lane = tid & 63, w = tid >> 6;     // w in 0..7
  const int g = lane >> 4, ql = lane & 15;
  const int bid = blockIdx.x;                  // 512 = 8 xcd x 8 bh-sub x 8 qt
  const int bh = (bid & 7) * 8 + ((bid >> 3) & 7);
  const int qt = bid >> 6;                     // 0..7
  const int b = bh >> 4, h = bh & 15;
  const int q0 = qt * 128;
  const int xr = ql & 7;

  // stage tile 0 into buf0: 512 threads cover 8KB K + 8KB V in one gload each
  {
    int o = tid * 16;
    int row = o >> 7, ch = (o >> 4) & 7;
    gload16(KKp + (size_t)(b * S_ + row) * HID_ + h * DH_ + ((ch ^ (row & 7)) * 8),
            smem + w * 1024);
    gload16(Vt + (size_t)(bh * DH_ + row) * S_ + ((ch ^ (row & 7)) * 8),
            smem + 8192 + w * 1024);
  }
  // mask row -> additive f32 in LDS (once)
  {
    int2 mv2 = *(const int2*)(mask + b * S_ + tid * 2);
    float2 f;
    f.x = mv2.x ? 0.f : -1e9f;
    f.y = mv2.y ? 0.f : -1e9f;
    *(float2*)(smem + 49152 + tid * 8) = f;
  }

  const u16* qrow = Qp + (size_t)(b * S_ + q0 + w * 16 + ql) * HID_ + h * DH_;
  bf16x8 qb0 = *(const bf16x8*)(qrow + g * 8);
  bf16x8 qb1 = *(const bf16x8*)(qrow + 32 + g * 8);

  f32x4 oacc[4];
  #pragma unroll
  for (int d = 0; d < 4; ++d) oacc[d] = f32x4{0.f, 0.f, 0.f, 0.f};
  float m_run = -1e30f, l_run = 0.f;
  char* pbase = smem + 32768 + w * 2048 + ql * 128;
  const char* madd_l = smem + 49152;

  __syncthreads();   // publish madd (drains prologue stage too; iter-0 waits trivially pass)

  int pb = 0;
  #pragma unroll 1
  for (int it = 0; it < 16; ++it) {
    const int k0 = it * 64;
    if (it < 15) {
      const int k0s = k0 + 64;
      const int bo = (pb ^ 1) * 16384;
      int o = tid * 16;
      int row = o >> 7, ch = (o >> 4) & 7;
      gload16(KKp + (size_t)(b * S_ + k0s + row) * HID_ + h * DH_ + ((ch ^ (row & 7)) * 8),
              smem + bo + w * 1024);
      gload16(Vt + (size_t)(bh * DH_ + row) * S_ + k0s + ((ch ^ (row & 7)) * 8),
              smem + bo + 8192 + w * 1024);
      asm volatile("s_waitcnt vmcnt(2)" ::: "memory");
    } else {
      asm volatile("s_waitcnt vmcnt(0)" ::: "memory");
    }
    __builtin_amdgcn_s_barrier();

    const char* kb_ = smem + pb * 16384;
    const char* vb_ = smem + pb * 16384 + 8192;

    float sv[4][4];
    #pragma unroll
    for (int t = 0; t < 4; ++t) {
      const char* krow = kb_ + (16 * t + ql) * 128;
      bf16x8 ka0 = *(const bf16x8*)(krow + ((g ^ xr) * 16));
      bf16x8 ka1 = *(const bf16x8*)(krow + (((4 + g) ^ xr) * 16));
      f32x4 st = mfma16(ka0, qb0, f32x4{0.f, 0.f, 0.f, 0.f});
      st = mfma16(ka1, qb1, st);
      f32x4 md = *(const f32x4*)(madd_l + (k0 + 16 * t + 4 * g) * 4);
      sv[t][0] = st[0] + md[0];
      sv[t][1] = st[1] + md[1];
      sv[t][2] = st[2] + md[2];
      sv[t][3] = st[3] + md[3];
    }
    float mloc = sv[0][0];
    #pragma unroll
    for (int t = 0; t < 4; ++t)
      #pragma unroll
      for (int i = 0; i < 4; ++i) mloc = fmaxf(mloc, sv[t][i]);
    mloc = fmaxf(mloc, __shfl_xor(mloc, 16, 64));
    mloc = fmaxf(mloc, __shfl_xor(mloc, 32, 64));
    if (__any(mloc > m_run + 10.f)) {
      float mnew = fmaxf(m_run, mloc);
      float alpha = __builtin_amdgcn_exp2f(m_run - mnew);
      l_run *= alpha;
      #pragma unroll
      for (int d = 0; d < 4; ++d) oacc[d] *= alpha;
      m_run = mnew;
    }
    float rsum = 0.f;
    float pvs[4][4];
    #pragma unroll
    for (int t = 0; t < 4; ++t)
      #pragma unroll
      for (int i = 0; i < 4; ++i) {
        float p = __builtin_amdgcn_exp2f(sv[t][i] - m_run);
        pvs[t][i] = p; rsum += p;
      }
    rsum += __shfl_xor(rsum, 16, 64);
    rsum += __shfl_xor(rsum, 32, 64);
    l_run += rsum;

    #pragma unroll
    for (int t = 0; t < 4; ++t) {
      uint2 pw;
      pw.x = cvtpk(pvs[t][0], pvs[t][1]);
      pw.y = cvtpk(pvs[t][2], pvs[t][3]);
      *(uint2*)(pbase + (((4 * t + g) ^ (2 * xr)) * 8)) = pw;
    }
    #pragma unroll
    for (int c = 0; c < 2; ++c) {
      bf16x8 pf = *(const bf16x8*)(pbase + (((c * 4 + g) ^ xr) * 16));
      #pragma unroll
      for (int d = 0; d < 4; ++d) {
        bf16x8 va = *(const bf16x8*)(vb_ + (16 * d + ql) * 128 + (((c * 4 + g) ^ xr) * 16));
        oacc[d] = mfma16(va, pf, oacc[d]);
      }
    }
    __builtin_amdgcn_s_barrier();
    pb ^= 1;
  }

  float inv = 1.0f / l_run;
  char* ep = smem + w * 2304;
  #pragma unroll
  for (int d = 0; d < 4; ++d)
    #pragma unroll
    for (int i = 0; i < 4; ++i)
      *(u16*)(ep + ql * 144 + (16 * d + 4 * g + i) * 2) = f2bf(oacc[d][i] * inv);
  __syncthreads();
  int r = lane >> 2, cc = lane & 3;
  const char* erow = smem + w * 2304 + r * 144 + cc * 32;
  uint4 v0 = *(const uint4*)erow;
  uint4 v1 = *(const uint4*)(erow + 16);
  u16* orow = hidden + (size_t)(b * S_ + q0 + w * 16 + r) * HID_ + h * DH_ + cc * 16;
  *(uint4*)orow = v0;
  *(uint4*)(orow + 8) = v1;
}

// ---------------- launch ----------------
extern "C" void kernel_launch(void* const* d_in, const int* in_sizes, int n_in,
                              void* d_out, int out_size, void* d_ws, size_t ws_size,
                              hipStream_t stream) {
  (void)in_sizes; (void)n_in; (void)out_size; (void)ws_size;
  const float* q    = (const float*)d_in[0];
  const float* k    = (const float*)d_in[1];
  const float* v    = (const float*)d_in[2];
  const float* kb   = (const float*)d_in[3];
  const int*   mask = (const int*)  d_in[4];
  const float* Wq   = (const float*)d_in[5];
  const float* bq   = (const float*)d_in[6];
  const float* Wk   = (const float*)d_in[7];
  const float* bk   = (const float*)d_in[8];
  const float* Wv   = (const float*)d_in[9];
  const float* bv   = (const float*)d_in[10];
  const float* Wkb  = (const float*)d_in[11];
  const float* bkb  = (const float*)d_in[12];
  const float* Wo   = (const float*)d_in[13];
  const float* bo   = (const float*)d_in[14];

  char* ws = (char*)d_ws;
  const size_t MB = 1024 * 1024;
  u16* qbf   = (u16*)(ws + 0 * MB);
  u16* kbf   = (u16*)(ws + 8 * MB);
  u16* vbf   = (u16*)(ws + 16 * MB);
  u16* kbbf  = (u16*)(ws + 24 * MB);
  u16* Wqbf  = (u16*)(ws + 32 * MB);
  u16* Wkbf  = (u16*)(ws + 34 * MB);
  u16* Wvbf  = (u16*)(ws + 36 * MB);
  u16* Wkbbf = (u16*)(ws + 38 * MB);
  u16* Wobf  = (u16*)(ws + 40 * MB);
  u16* Qp    = (u16*)(ws + 42 * MB);
  u16* KKp   = (u16*)(ws + 50 * MB);
  u16* Vtp   = (u16*)(ws + 58 * MB);
  u16* hid   = (u16*)(ws + 66 * MB);

  cvt_all<<<10752, 256, 0, stream>>>(q, k, v, kb, Wq, Wk, Wv, Wkb, Wo,
                                     qbf, kbf, vbf, kbbf, Wqbf, Wkbf, Wvbf, Wkbbf, Wobf);
  gemm_proj<<<1536, 256, 0, stream>>>(qbf, Wqbf, kbf, Wkbf, kbbf, Wkbbf, vbf, Wvbf,
                                      bq, bk, bkb, bv, Qp, KKp, Vtp);
  attn<<<512, 512, 0, stream>>>(Qp, KKp, Vtp, mask, hid);
  gemm_o<<<512, 256, 0, stream>>>(hid, Wobf, bo, (float*)d_out);
}

// Round 16
// 113.711 us; speedup vs baseline: 1.3478x; 1.0206x over previous
//
#include <hip/hip_runtime.h>
#include <hip/hip_bf16.h>
#include <stdint.h>

#define B_   4
#define S_   1024
#define HID_ 1024
#define H_   16
#define DH_  64

typedef short bf16x8 __attribute__((ext_vector_type(8)));
typedef float f32x4  __attribute__((ext_vector_type(4)));
typedef unsigned int u32;
typedef unsigned short u16;

typedef u32 __attribute__((address_space(1))) as1_u32;
typedef u32 __attribute__((address_space(3))) as3_u32;

__device__ __forceinline__ f32x4 mfma16(bf16x8 a, bf16x8 b, f32x4 c) {
  return __builtin_amdgcn_mfma_f32_16x16x32_bf16(a, b, c, 0, 0, 0);
}

__device__ __forceinline__ void gload16(const void* g, void* l) {
  __builtin_amdgcn_global_load_lds((const as1_u32*)g, (as3_u32*)l, 16, 0, 0);
}

__device__ __forceinline__ u16 f2bf(float f) {
  __hip_bfloat16 h = __float2bfloat16(f);
  union { __hip_bfloat16 h; u16 u; } cv; cv.h = h; return cv.u;
}

__device__ __forceinline__ u32 cvtpk(float lo, float hi) {
  u32 r;
  asm("v_cvt_pk_bf16_f32 %0, %1, %2" : "=v"(r) : "v"(lo), "v"(hi));
  return r;
}

// stage a [NC*32 x 64] bf16 tile into LDS at byte offset bo (XOR-swizzled source)
template<int NC>
__device__ __forceinline__ void stage_tile(const u16* __restrict__ src, char* smem, int bo,
                                           int tid, int w) {
  #pragma unroll
  for (int is = 0; is < NC; ++is) {
    int o = is * 4096 + tid * 16;
    int row = o >> 7, ch = (o >> 4) & 7;
    gload16(src + (size_t)row * HID_ + ((ch ^ (row & 7)) * 8),
            smem + bo + is * 4096 + w * 1024);
  }
}

// ---------------- converts ----------------
__global__ __launch_bounds__(256) void cvt_all(
    const float* a0, const float* a1, const float* a2, const float* a3,
    const float* w0, const float* w1, const float* w2, const float* w3, const float* w4,
    u16* da0, u16* da1, u16* da2, u16* da3,
    u16* dw0, u16* dw1, u16* dw2, u16* dw3, u16* dw4) {
  int bb = blockIdx.x;
  const float* s; u16* d; size_t i;
  if (bb < 8192) {
    int t = bb * 256 + threadIdx.x;
    int sel = t >> 19;
    i = (size_t)(t & 524287) * 8;
    if (sel == 0)      { s = a0; d = da0; }
    else if (sel == 1) { s = a1; d = da1; }
    else if (sel == 2) { s = a2; d = da2; }
    else               { s = a3; d = da3; }
  } else {
    int t = (bb - 8192) * 256 + threadIdx.x;
    int sel = t >> 17;
    i = (size_t)(t & 131071) * 8;
    if (sel == 0)      { s = w0; d = dw0; }
    else if (sel == 1) { s = w1; d = dw1; }
    else if (sel == 2) { s = w2; d = dw2; }
    else if (sel == 3) { s = w3; d = dw3; }
    else               { s = w4; d = dw4; }
  }
  float4 v0 = *(const float4*)(s + i);
  float4 v1 = *(const float4*)(s + i + 4);
  uint4 r;
  r.x = cvtpk(v0.x, v0.y);
  r.y = cvtpk(v0.z, v0.w);
  r.z = cvtpk(v1.x, v1.y);
  r.w = cvtpk(v1.z, v1.w);
  *(uint4*)(d + i) = r;
}

// ---------------- fused projection GEMM: uniform 128x64 tiles, 48KB dbuf, 3 blocks/CU ----------
__global__ __launch_bounds__(256, 3) void gemm_proj(
    const u16* __restrict__ qbf, const u16* __restrict__ Wqbf,
    const u16* __restrict__ kbf, const u16* __restrict__ Wkbf,
    const u16* __restrict__ kbbf, const u16* __restrict__ Wkbbf,
    const u16* __restrict__ vbf, const u16* __restrict__ Wvbf,
    const float* __restrict__ bq, const float* __restrict__ bk,
    const float* __restrict__ bkb, const float* __restrict__ bv,
    u16* __restrict__ Qp, u16* __restrict__ KKp, u16* __restrict__ Vtp) {
  __shared__ __align__(16) char smem[49152];
  const int tid = threadIdx.x;
  const int lane = tid & 63, w = tid >> 6;
  const int g = lane >> 4, ql = lane & 15;
  const int wm = w >> 1, wn = w & 1;
  const int xr = ql & 7;
  const int xcd = blockIdx.x & 7, idx = blockIdx.x >> 3;
  const int unit = (idx < 64) ? 0 : (idx < 128) ? 1 : 2;   // 0 KK, 1 Q, 2 V
  const int id = xcd * 64 + (idx & 63);
  const int m0 = (id >> 4) * 128;
  const int n0 = (id & 15) * 64;

  const u16 *A0, *W0, *A1, *W1;
  int nkt;
  if (unit == 0)      { A0 = kbf; W0 = Wkbf; A1 = kbbf; W1 = Wkbbf; nkt = 32; }
  else if (unit == 1) { A0 = qbf; W0 = Wqbf; A1 = qbf;  W1 = Wqbf;  nkt = 16; }
  else                { A0 = vbf; W0 = Wvbf; A1 = vbf;  W1 = Wvbf;  nkt = 16; }

  f32x4 acc[4][2];
  #pragma unroll
  for (int mi = 0; mi < 4; ++mi)
    #pragma unroll
    for (int ni = 0; ni < 2; ++ni) acc[mi][ni] = f32x4{0.f, 0.f, 0.f, 0.f};

  stage_tile<4>(A0 + (size_t)m0 * HID_, smem, 0, tid, w);
  stage_tile<2>(W0 + (size_t)n0 * HID_, smem, 16384, tid, w);

  #pragma unroll 1
  for (int kt = 0; kt < nkt; ++kt) {
    const int boA = (kt & 1) ? 24576 : 0;
    const int boW = (kt & 1) ? 40960 : 16384;
    if (kt < nkt - 1) {
      int kn = kt + 1;
      const u16* As = (kn < 16) ? A0 : A1;
      const u16* Ws = (kn < 16) ? W0 : W1;
      int kk = (kn & 15) * 64;
      stage_tile<4>(As + (size_t)m0 * HID_ + kk, smem, boA ^ 24576, tid, w);
      stage_tile<2>(Ws + (size_t)n0 * HID_ + kk, smem, boW ^ (16384 ^ 40960), tid, w);
      asm volatile("s_waitcnt vmcnt(6)" ::: "memory");
    } else {
      asm volatile("s_waitcnt vmcnt(0)" ::: "memory");
    }
    __builtin_amdgcn_s_barrier();
    const char* ab = smem + boA;
    const char* wb = smem + boW;
    bf16x8 af[4][2], bfv[2][2];
    #pragma unroll
    for (int mi = 0; mi < 4; ++mi)
      #pragma unroll
      for (int c = 0; c < 2; ++c) {
        int row = wm * 64 + mi * 16 + ql;
        af[mi][c] = *(const bf16x8*)(ab + row * 128 + (((c * 4 + g) ^ xr) * 16));
      }
    #pragma unroll
    for (int ni = 0; ni < 2; ++ni)
      #pragma unroll
      for (int c = 0; c < 2; ++c) {
        int row = wn * 32 + ni * 16 + ql;
        bfv[ni][c] = *(const bf16x8*)(wb + row * 128 + (((c * 4 + g) ^ xr) * 16));
      }
    __builtin_amdgcn_s_setprio(1);
    #pragma unroll
    for (int c = 0; c < 2; ++c)
      #pragma unroll
      for (int mi = 0; mi < 4; ++mi)
        #pragma unroll
        for (int ni = 0; ni < 2; ++ni)
          acc[mi][ni] = mfma16(af[mi][c], bfv[ni][c], acc[mi][ni]);
    __builtin_amdgcn_s_setprio(0);
    __builtin_amdgcn_s_barrier();
  }

  if (unit != 2) {
    u16* outp = (unit == 0) ? KKp : Qp;
    const float osc = (unit == 1) ? 0.07216878364870322f * 1.44269504088896340f : 1.f;
    #pragma unroll
    for (int ni = 0; ni < 2; ++ni) {
      int n = n0 + wn * 32 + ni * 16 + ql;
      float bs = (unit == 0) ? (bk[n] + bkb[n]) : bq[n];
      #pragma unroll
      for (int mi = 0; mi < 4; ++mi)
        #pragma unroll
        for (int i = 0; i < 4; ++i) {
          int m = m0 + wm * 64 + mi * 16 + g * 4 + i;
          outp[(size_t)m * HID_ + n] = f2bf((acc[mi][ni][i] + bs) * osc);
        }
    }
  } else {
    char* tp = smem + w * 4096;
    #pragma unroll
    for (int ni = 0; ni < 2; ++ni) {
      int n = n0 + wn * 32 + ni * 16 + ql;
      float bs = bv[n];
      #pragma unroll
      for (int mi = 0; mi < 4; ++mi)
        #pragma unroll
        for (int i = 0; i < 4; ++i) {
          int nl = ni * 16 + ql;
          int ml = mi * 16 + g * 4 + i;
          *(u16*)(tp + nl * 128 + (((ml >> 3) ^ (nl & 7)) * 16) + (ml & 7) * 2) =
              f2bf(acc[mi][ni][i] + bs);
        }
    }
    __syncthreads();
    int r = lane >> 1, half = lane & 1;
    int n = n0 + wn * 32 + r;
    int h = n >> 6, dh = n & 63;
    int b = m0 >> 10;
    int bh = b * H_ + h;
    u16* orow = Vtp + (((size_t)(bh * DH_ + dh)) << 10) + (m0 & 1023) + wm * 64 + half * 32;
    #pragma unroll
    for (int j = 0; j < 4; ++j) {
      uint4 val = *(const uint4*)(tp + r * 128 + (((half * 4 + j) ^ (r & 7)) * 16));
      *(uint4*)(orow + j * 8) = val;
    }
  }
}

// ---------------- O GEMM (128x64 tile, bf16 in, f32 out, dbuf + counted vmcnt) ----------------
__global__ __launch_bounds__(256, 3) void gemm_o(const u16* __restrict__ A0, const u16* __restrict__ W0,
                                                 const float* __restrict__ bias0, float* __restrict__ outp) {
  __shared__ __align__(16) char smem[49152];
  const int tid = threadIdx.x;
  const int lane = tid & 63, w = tid >> 6;
  const int g = lane >> 4, ql = lane & 15;
  const int wm = w >> 1, wn = w & 1;
  const int logical = (blockIdx.x & 7) * 64 + (blockIdx.x >> 3);
  const int m0 = (logical >> 4) * 128;
  const int n0 = (logical & 15) * 64;
  const int xr = ql & 7;

  f32x4 acc[4][2];
  #pragma unroll
  for (int mi = 0; mi < 4; ++mi)
    #pragma unroll
    for (int ni = 0; ni < 2; ++ni) acc[mi][ni] = f32x4{0.f, 0.f, 0.f, 0.f};

  stage_tile<4>(A0 + (size_t)m0 * HID_, smem, 0, tid, w);
  stage_tile<2>(W0 + (size_t)n0 * HID_, smem, 16384, tid, w);

  #pragma unroll 1
  for (int kt = 0; kt < 16; ++kt) {
    const int boA = (kt & 1) ? 24576 : 0;
    const int boW = (kt & 1) ? 40960 : 16384;
    if (kt < 15) {
      int kk = (kt + 1) * 64;
      stage_tile<4>(A0 + (size_t)m0 * HID_ + kk, smem, boA ^ 24576, tid, w);
      stage_tile<2>(W0 + (size_t)n0 * HID_ + kk, smem, boW ^ (16384 ^ 40960), tid, w);
      asm volatile("s_waitcnt vmcnt(6)" ::: "memory");
    } else {
      asm volatile("s_waitcnt vmcnt(0)" ::: "memory");
    }
    __builtin_amdgcn_s_barrier();
    const char* ab = smem + boA;
    const char* wb = smem + boW;
    bf16x8 af[4][2], bfv[2][2];
    #pragma unroll
    for (int mi = 0; mi < 4; ++mi)
      #pragma unroll
      for (int c = 0; c < 2; ++c) {
        int row = wm * 64 + mi * 16 + ql;
        af[mi][c] = *(const bf16x8*)(ab + row * 128 + (((c * 4 + g) ^ xr) * 16));
      }
    #pragma unroll
    for (int ni = 0; ni < 2; ++ni)
      #pragma unroll
      for (int c = 0; c < 2; ++c) {
        int row = wn * 32 + ni * 16 + ql;
        bfv[ni][c] = *(const bf16x8*)(wb + row * 128 + (((c * 4 + g) ^ xr) * 16));
      }
    __builtin_amdgcn_s_setprio(1);
    #pragma unroll
    for (int c = 0; c < 2; ++c)
      #pragma unroll
      for (int mi = 0; mi < 4; ++mi)
        #pragma unroll
        for (int ni = 0; ni < 2; ++ni)
          acc[mi][ni] = mfma16(af[mi][c], bfv[ni][c], acc[mi][ni]);
    __builtin_amdgcn_s_setprio(0);
    __builtin_amdgcn_s_barrier();
  }

  #pragma unroll
  for (int ni = 0; ni < 2; ++ni) {
    int n = n0 + wn * 32 + ni * 16 + ql;
    float bs = bias0[n];
    #pragma unroll
    for (int mi = 0; mi < 4; ++mi)
      #pragma unroll
      for (int i = 0; i < 4; ++i) {
        int m = m0 + wm * 64 + mi * 16 + g * 4 + i;
        outp[(size_t)m * HID_ + n] = acc[mi][ni][i] + bs;
      }
  }
}

// ---------------- flash attention: R14 skeleton + DEPTH-2 KV prefetch (3 buffers) ------------
// R15 bug fixed: K-tile offset is a ROW offset (scale by HID_); V-tile offset is a column
// offset (flat). Same proven loop body; vmcnt(4/2/0) depth-2 accounting; 3-buffer rotation.
__global__ __launch_bounds__(512, 6) void attn(const u16* __restrict__ Qp, const u16* __restrict__ KKp,
                                               const u16* __restrict__ Vt, const int* __restrict__ mask,
                                               u16* __restrict__ hidden) {
  __shared__ __align__(16) char smem[69632];   // bufs 0/1/2 @ i*16384 (K@+0,V@+8192); P@49152; madd@65536
  const int tid = threadIdx.x;
  const int lane = tid & 63, w = tid >> 6;     // w in 0..7
  const int g = lane >> 4, ql = lane & 15;
  const int bid = blockIdx.x;                  // 512 = 8 xcd x 8 bh-sub x 8 qt
  const int bh = (bid & 7) * 8 + ((bid >> 3) & 7);
  const int qt = bid >> 6;                     // 0..7
  const int b = bh >> 4, h = bh & 15;
  const int q0 = qt * 128;
  const int xr = ql & 7;
  const int o = tid * 16;
  const int srow = o >> 7, sch = (o >> 4) & 7;
  const size_t kgbase = (size_t)(b * S_ + srow) * HID_ + h * DH_ + ((sch ^ (srow & 7)) * 8);
  const size_t vgbase = (size_t)(bh * DH_ + srow) * S_ + ((sch ^ (srow & 7)) * 8);

  // prologue: stage tiles 0 and 1
  gload16(KKp + kgbase, smem + w * 1024);
  gload16(Vt + vgbase, smem + 8192 + w * 1024);
  gload16(KKp + kgbase + (size_t)64 * HID_, smem + 16384 + w * 1024);
  gload16(Vt + vgbase + 64, smem + 16384 + 8192 + w * 1024);
  // mask row -> additive f32 in LDS (once)
  {
    int2 mv2 = *(const int2*)(mask + b * S_ + tid * 2);
    float2 f;
    f.x = mv2.x ? 0.f : -1e9f;
    f.y = mv2.y ? 0.f : -1e9f;
    *(float2*)(smem + 65536 + tid * 8) = f;
  }

  const u16* qrow = Qp + (size_t)(b * S_ + q0 + w * 16 + ql) * HID_ + h * DH_;
  bf16x8 qb0 = *(const bf16x8*)(qrow + g * 8);
  bf16x8 qb1 = *(const bf16x8*)(qrow + 32 + g * 8);

  f32x4 oacc[4];
  #pragma unroll
  for (int d = 0; d < 4; ++d) oacc[d] = f32x4{0.f, 0.f, 0.f, 0.f};
  float m_run = -1e30f, l_run = 0.f;
  char* pbase = smem + 49152 + w * 2048 + ql * 128;
  const char* madd_l = smem + 65536;

  __syncthreads();   // publish madd (drains prologue stages; waits below are then trivial)

  int cur = 0, st = 2;
  #pragma unroll 1
  for (int it = 0; it < 16; ++it) {
    const int k0 = it * 64;
    if (it < 14) {
      const int k0s = k0 + 128;
      const int bo = st * 16384;
      gload16(KKp + kgbase + (size_t)k0s * HID_, smem + bo + w * 1024);
      gload16(Vt + vgbase + k0s, smem + bo + 8192 + w * 1024);
      asm volatile("s_waitcnt vmcnt(4)" ::: "memory");
    } else if (it == 14) {
      asm volatile("s_waitcnt vmcnt(2)" ::: "memory");
    } else {
      asm volatile("s_waitcnt vmcnt(0)" ::: "memory");
    }
    __builtin_amdgcn_s_barrier();

    const char* kb_ = smem + cur * 16384;
    const char* vb_ = smem + cur * 16384 + 8192;

    float sv[4][4];
    #pragma unroll
    for (int t = 0; t < 4; ++t) {
      const char* krow = kb_ + (16 * t + ql) * 128;
      bf16x8 ka0 = *(const bf16x8*)(krow + ((g ^ xr) * 16));
      bf16x8 ka1 = *(const bf16x8*)(krow + (((4 + g) ^ xr) * 16));
      f32x4 stv = mfma16(ka0, qb0, f32x4{0.f, 0.f, 0.f, 0.f});
      stv = mfma16(ka1, qb1, stv);
      f32x4 md = *(const f32x4*)(madd_l + (k0 + 16 * t + 4 * g) * 4);
      sv[t][0] = stv[0] + md[0];
      sv[t][1] = stv[1] + md[1];
      sv[t][2] = stv[2] + md[2];
      sv[t][3] = stv[3] + md[3];
    }
    float mloc = sv[0][0];
    #pragma unroll
    for (int t = 0; t < 4; ++t)
      #pragma unroll
      for (int i = 0; i < 4; ++i) mloc = fmaxf(mloc, sv[t][i]);
    mloc = fmaxf(mloc, __shfl_xor(mloc, 16, 64));
    mloc = fmaxf(mloc, __shfl_xor(mloc, 32, 64));
    if (__any(mloc > m_run + 10.f)) {
      float mnew = fmaxf(m_run, mloc);
      float alpha = __builtin_amdgcn_exp2f(m_run - mnew);
      l_run *= alpha;
      #pragma unroll
      for (int d = 0; d < 4; ++d) oacc[d] *= alpha;
      m_run = mnew;
    }
    float rsum = 0.f;
    float pvs[4][4];
    #pragma unroll
    for (int t = 0; t < 4; ++t)
      #pragma unroll
      for (int i = 0; i < 4; ++i) {
        float p = __builtin_amdgcn_exp2f(sv[t][i] - m_run);
        pvs[t][i] = p; rsum += p;
      }
    rsum += __shfl_xor(rsum, 16, 64);
    rsum += __shfl_xor(rsum, 32, 64);
    l_run += rsum;

    #pragma unroll
    for (int t = 0; t < 4; ++t) {
      uint2 pw;
      pw.x = cvtpk(pvs[t][0], pvs[t][1]);
      pw.y = cvtpk(pvs[t][2], pvs[t][3]);
      *(uint2*)(pbase + (((4 * t + g) ^ (2 * xr)) * 8)) = pw;
    }
    #pragma unroll
    for (int c = 0; c < 2; ++c) {
      bf16x8 pf = *(const bf16x8*)(pbase + (((c * 4 + g) ^ xr) * 16));
      #pragma unroll
      for (int d = 0; d < 4; ++d) {
        bf16x8 va = *(const bf16x8*)(vb_ + (16 * d + ql) * 128 + (((c * 4 + g) ^ xr) * 16));
        oacc[d] = mfma16(va, pf, oacc[d]);
      }
    }
    __builtin_amdgcn_s_barrier();
    cur = (cur == 2) ? 0 : cur + 1;
    st  = (st == 2) ? 0 : st + 1;
  }

  float inv = 1.0f / l_run;
  char* ep = smem + w * 2304;
  #pragma unroll
  for (int d = 0; d < 4; ++d)
    #pragma unroll
    for (int i = 0; i < 4; ++i)
      *(u16*)(ep + ql * 144 + (16 * d + 4 * g + i) * 2) = f2bf(oacc[d][i] * inv);
  __syncthreads();
  int r = lane >> 2, cc = lane & 3;
  const char* erow = smem + w * 2304 + r * 144 + cc * 32;
  uint4 v0 = *(const uint4*)erow;
  uint4 v1 = *(const uint4*)(erow + 16);
  u16* orow = hidden + (size_t)(b * S_ + q0 + w * 16 + r) * HID_ + h * DH_ + cc * 16;
  *(uint4*)orow = v0;
  *(uint4*)(orow + 8) = v1;
}

// ---------------- launch ----------------
extern "C" void kernel_launch(void* const* d_in, const int* in_sizes, int n_in,
                              void* d_out, int out_size, void* d_ws, size_t ws_size,
                              hipStream_t stream) {
  (void)in_sizes; (void)n_in; (void)out_size; (void)ws_size;
  const float* q    = (const float*)d_in[0];
  const float* k    = (const float*)d_in[1];
  const float* v    = (const float*)d_in[2];
  const float* kb   = (const float*)d_in[3];
  const int*   mask = (const int*)  d_in[4];
  const float* Wq   = (const float*)d_in[5];
  const float* bq   = (const float*)d_in[6];
  const float* Wk   = (const float*)d_in[7];
  const float* bk   = (const float*)d_in[8];
  const float* Wv   = (const float*)d_in[9];
  const float* bv   = (const float*)d_in[10];
  const float* Wkb  = (const float*)d_in[11];
  const float* bkb  = (const float*)d_in[12];
  const float* Wo   = (const float*)d_in[13];
  const float* bo   = (const float*)d_in[14];

  char* ws = (char*)d_ws;
  const size_t MB = 1024 * 1024;
  u16* qbf   = (u16*)(ws + 0 * MB);
  u16* kbf   = (u16*)(ws + 8 * MB);
  u16* vbf   = (u16*)(ws + 16 * MB);
  u16* kbbf  = (u16*)(ws + 24 * MB);
  u16* Wqbf  = (u16*)(ws + 32 * MB);
  u16* Wkbf  = (u16*)(ws + 34 * MB);
  u16* Wvbf  = (u16*)(ws + 36 * MB);
  u16* Wkbbf = (u16*)(ws + 38 * MB);
  u16* Wobf  = (u16*)(ws + 40 * MB);
  u16* Qp    = (u16*)(ws + 42 * MB);
  u16* KKp   = (u16*)(ws + 50 * MB);
  u16* Vtp   = (u16*)(ws + 58 * MB);
  u16* hid   = (u16*)(ws + 66 * MB);

  cvt_all<<<10752, 256, 0, stream>>>(q, k, v, kb, Wq, Wk, Wv, Wkb, Wo,
                                     qbf, kbf, vbf, kbbf, Wqbf, Wkbf, Wvbf, Wkbbf, Wobf);
  gemm_proj<<<1536, 256, 0, stream>>>(qbf, Wqbf, kbf, Wkbf, kbbf, Wkbbf, vbf, Wvbf,
                                      bq, bk, bkb, bv, Qp, KKp, Vtp);
  attn<<<512, 512, 0, stream>>>(Qp, KKp, Vtp, mask, hid);
  gemm_o<<<512, 256, 0, stream>>>(hid, Wobf, bo, (float*)d_out);
}

// Round 17
// 112.971 us; speedup vs baseline: 1.3566x; 1.0065x over previous
//
#include <hip/hip_runtime.h>
#include <hip/hip_bf16.h>
#include <stdint.h>

#define B_   4
#define S_   1024
#define HID_ 1024
#define H_   16
#define DH_  64

typedef short bf16x8 __attribute__((ext_vector_type(8)));
typedef float f32x4  __attribute__((ext_vector_type(4)));
typedef unsigned int u32;
typedef unsigned short u16;

typedef u32 __attribute__((address_space(1))) as1_u32;
typedef u32 __attribute__((address_space(3))) as3_u32;

__device__ __forceinline__ f32x4 mfma16(bf16x8 a, bf16x8 b, f32x4 c) {
  return __builtin_amdgcn_mfma_f32_16x16x32_bf16(a, b, c, 0, 0, 0);
}

__device__ __forceinline__ void gload16(const void* g, void* l) {
  __builtin_amdgcn_global_load_lds((const as1_u32*)g, (as3_u32*)l, 16, 0, 0);
}

__device__ __forceinline__ u16 f2bf(float f) {
  __hip_bfloat16 h = __float2bfloat16(f);
  union { __hip_bfloat16 h; u16 u; } cv; cv.h = h; return cv.u;
}

__device__ __forceinline__ u32 cvtpk(float lo, float hi) {
  u32 r;
  asm("v_cvt_pk_bf16_f32 %0, %1, %2" : "=v"(r) : "v"(lo), "v"(hi));
  return r;
}

// stage a [NC*32 x 64] bf16 tile into LDS at byte offset bo (XOR-swizzled source)
template<int NC>
__device__ __forceinline__ void stage_tile(const u16* __restrict__ src, char* smem, int bo,
                                           int tid, int w) {
  #pragma unroll
  for (int is = 0; is < NC; ++is) {
    int o = is * 4096 + tid * 16;
    int row = o >> 7, ch = (o >> 4) & 7;
    gload16(src + (size_t)row * HID_ + ((ch ^ (row & 7)) * 8),
            smem + bo + is * 4096 + w * 1024);
  }
}

// ---------------- converts ----------------
__global__ __launch_bounds__(256) void cvt_all(
    const float* a0, const float* a1, const float* a2, const float* a3,
    const float* w0, const float* w1, const float* w2, const float* w3, const float* w4,
    u16* da0, u16* da1, u16* da2, u16* da3,
    u16* dw0, u16* dw1, u16* dw2, u16* dw3, u16* dw4) {
  int bb = blockIdx.x;
  const float* s; u16* d; size_t i;
  if (bb < 8192) {
    int t = bb * 256 + threadIdx.x;
    int sel = t >> 19;
    i = (size_t)(t & 524287) * 8;
    if (sel == 0)      { s = a0; d = da0; }
    else if (sel == 1) { s = a1; d = da1; }
    else if (sel == 2) { s = a2; d = da2; }
    else               { s = a3; d = da3; }
  } else {
    int t = (bb - 8192) * 256 + threadIdx.x;
    int sel = t >> 17;
    i = (size_t)(t & 131071) * 8;
    if (sel == 0)      { s = w0; d = dw0; }
    else if (sel == 1) { s = w1; d = dw1; }
    else if (sel == 2) { s = w2; d = dw2; }
    else if (sel == 3) { s = w3; d = dw3; }
    else               { s = w4; d = dw4; }
  }
  float4 v0 = *(const float4*)(s + i);
  float4 v1 = *(const float4*)(s + i + 4);
  uint4 r;
  r.x = cvtpk(v0.x, v0.y);
  r.y = cvtpk(v0.z, v0.w);
  r.z = cvtpk(v1.x, v1.y);
  r.w = cvtpk(v1.z, v1.w);
  *(uint4*)(d + i) = r;
}

// ---------------- fused projection GEMM: uniform 128x64 tiles, 48KB dbuf, 3 blocks/CU ----------
__global__ __launch_bounds__(256, 3) void gemm_proj(
    const u16* __restrict__ qbf, const u16* __restrict__ Wqbf,
    const u16* __restrict__ kbf, const u16* __restrict__ Wkbf,
    const u16* __restrict__ kbbf, const u16* __restrict__ Wkbbf,
    const u16* __restrict__ vbf, const u16* __restrict__ Wvbf,
    const float* __restrict__ bq, const float* __restrict__ bk,
    const float* __restrict__ bkb, const float* __restrict__ bv,
    u16* __restrict__ Qp, u16* __restrict__ KKp, u16* __restrict__ Vtp) {
  __shared__ __align__(16) char smem[49152];
  const int tid = threadIdx.x;
  const int lane = tid & 63, w = tid >> 6;
  const int g = lane >> 4, ql = lane & 15;
  const int wm = w >> 1, wn = w & 1;
  const int xr = ql & 7;
  const int xcd = blockIdx.x & 7, idx = blockIdx.x >> 3;
  const int unit = (idx < 64) ? 0 : (idx < 128) ? 1 : 2;   // 0 KK, 1 Q, 2 V
  const int id = xcd * 64 + (idx & 63);
  const int m0 = (id >> 4) * 128;
  const int n0 = (id & 15) * 64;

  const u16 *A0, *W0, *A1, *W1;
  int nkt;
  if (unit == 0)      { A0 = kbf; W0 = Wkbf; A1 = kbbf; W1 = Wkbbf; nkt = 32; }
  else if (unit == 1) { A0 = qbf; W0 = Wqbf; A1 = qbf;  W1 = Wqbf;  nkt = 16; }
  else                { A0 = vbf; W0 = Wvbf; A1 = vbf;  W1 = Wvbf;  nkt = 16; }

  f32x4 acc[4][2];
  #pragma unroll
  for (int mi = 0; mi < 4; ++mi)
    #pragma unroll
    for (int ni = 0; ni < 2; ++ni) acc[mi][ni] = f32x4{0.f, 0.f, 0.f, 0.f};

  stage_tile<4>(A0 + (size_t)m0 * HID_, smem, 0, tid, w);
  stage_tile<2>(W0 + (size_t)n0 * HID_, smem, 16384, tid, w);

  #pragma unroll 1
  for (int kt = 0; kt < nkt; ++kt) {
    const int boA = (kt & 1) ? 24576 : 0;
    const int boW = (kt & 1) ? 40960 : 16384;
    if (kt < nkt - 1) {
      int kn = kt + 1;
      const u16* As = (kn < 16) ? A0 : A1;
      const u16* Ws = (kn < 16) ? W0 : W1;
      int kk = (kn & 15) * 64;
      stage_tile<4>(As + (size_t)m0 * HID_ + kk, smem, boA ^ 24576, tid, w);
      stage_tile<2>(Ws + (size_t)n0 * HID_ + kk, smem, boW ^ (16384 ^ 40960), tid, w);
      asm volatile("s_waitcnt vmcnt(6)" ::: "memory");
    } else {
      asm volatile("s_waitcnt vmcnt(0)" ::: "memory");
    }
    __builtin_amdgcn_s_barrier();
    const char* ab = smem + boA;
    const char* wb = smem + boW;
    bf16x8 af[4][2], bfv[2][2];
    #pragma unroll
    for (int mi = 0; mi < 4; ++mi)
      #pragma unroll
      for (int c = 0; c < 2; ++c) {
        int row = wm * 64 + mi * 16 + ql;
        af[mi][c] = *(const bf16x8*)(ab + row * 128 + (((c * 4 + g) ^ xr) * 16));
      }
    #pragma unroll
    for (int ni = 0; ni < 2; ++ni)
      #pragma unroll
      for (int c = 0; c < 2; ++c) {
        int row = wn * 32 + ni * 16 + ql;
        bfv[ni][c] = *(const bf16x8*)(wb + row * 128 + (((c * 4 + g) ^ xr) * 16));
      }
    __builtin_amdgcn_s_setprio(1);
    #pragma unroll
    for (int c = 0; c < 2; ++c)
      #pragma unroll
      for (int mi = 0; mi < 4; ++mi)
        #pragma unroll
        for (int ni = 0; ni < 2; ++ni)
          acc[mi][ni] = mfma16(af[mi][c], bfv[ni][c], acc[mi][ni]);
    __builtin_amdgcn_s_setprio(0);
    __builtin_amdgcn_s_barrier();
  }

  if (unit != 2) {
    u16* outp = (unit == 0) ? KKp : Qp;
    const float osc = (unit == 1) ? 0.07216878364870322f * 1.44269504088896340f : 1.f;
    #pragma unroll
    for (int ni = 0; ni < 2; ++ni) {
      int n = n0 + wn * 32 + ni * 16 + ql;
      float bs = (unit == 0) ? (bk[n] + bkb[n]) : bq[n];
      #pragma unroll
      for (int mi = 0; mi < 4; ++mi)
        #pragma unroll
        for (int i = 0; i < 4; ++i) {
          int m = m0 + wm * 64 + mi * 16 + g * 4 + i;
          outp[(size_t)m * HID_ + n] = f2bf((acc[mi][ni][i] + bs) * osc);
        }
    }
  } else {
    char* tp = smem + w * 4096;
    #pragma unroll
    for (int ni = 0; ni < 2; ++ni) {
      int n = n0 + wn * 32 + ni * 16 + ql;
      float bs = bv[n];
      #pragma unroll
      for (int mi = 0; mi < 4; ++mi)
        #pragma unroll
        for (int i = 0; i < 4; ++i) {
          int nl = ni * 16 + ql;
          int ml = mi * 16 + g * 4 + i;
          *(u16*)(tp + nl * 128 + (((ml >> 3) ^ (nl & 7)) * 16) + (ml & 7) * 2) =
              f2bf(acc[mi][ni][i] + bs);
        }
    }
    __syncthreads();
    int r = lane >> 1, half = lane & 1;
    int n = n0 + wn * 32 + r;
    int h = n >> 6, dh = n & 63;
    int b = m0 >> 10;
    int bh = b * H_ + h;
    u16* orow = Vtp + (((size_t)(bh * DH_ + dh)) << 10) + (m0 & 1023) + wm * 64 + half * 32;
    #pragma unroll
    for (int j = 0; j < 4; ++j) {
      uint4 val = *(const uint4*)(tp + r * 128 + (((half * 4 + j) ^ (r & 7)) * 16));
      *(uint4*)(orow + j * 8) = val;
    }
  }
}

// ---------------- O GEMM (128x64 tile, bf16 in, f32 out, dbuf + counted vmcnt) ----------------
__global__ __launch_bounds__(256, 3) void gemm_o(const u16* __restrict__ A0, const u16* __restrict__ W0,
                                                 const float* __restrict__ bias0, float* __restrict__ outp) {
  __shared__ __align__(16) char smem[49152];
  const int tid = threadIdx.x;
  const int lane = tid & 63, w = tid >> 6;
  const int g = lane >> 4, ql = lane & 15;
  const int wm = w >> 1, wn = w & 1;
  const int logical = (blockIdx.x & 7) * 64 + (blockIdx.x >> 3);
  const int m0 = (logical >> 4) * 128;
  const int n0 = (logical & 15) * 64;
  const int xr = ql & 7;

  f32x4 acc[4][2];
  #pragma unroll
  for (int mi = 0; mi < 4; ++mi)
    #pragma unroll
    for (int ni = 0; ni < 2; ++ni) acc[mi][ni] = f32x4{0.f, 0.f, 0.f, 0.f};

  stage_tile<4>(A0 + (size_t)m0 * HID_, smem, 0, tid, w);
  stage_tile<2>(W0 + (size_t)n0 * HID_, smem, 16384, tid, w);

  #pragma unroll 1
  for (int kt = 0; kt < 16; ++kt) {
    const int boA = (kt & 1) ? 24576 : 0;
    const int boW = (kt & 1) ? 40960 : 16384;
    if (kt < 15) {
      int kk = (kt + 1) * 64;
      stage_tile<4>(A0 + (size_t)m0 * HID_ + kk, smem, boA ^ 24576, tid, w);
      stage_tile<2>(W0 + (size_t)n0 * HID_ + kk, smem, boW ^ (16384 ^ 40960), tid, w);
      asm volatile("s_waitcnt vmcnt(6)" ::: "memory");
    } else {
      asm volatile("s_waitcnt vmcnt(0)" ::: "memory");
    }
    __builtin_amdgcn_s_barrier();
    const char* ab = smem + boA;
    const char* wb = smem + boW;
    bf16x8 af[4][2], bfv[2][2];
    #pragma unroll
    for (int mi = 0; mi < 4; ++mi)
      #pragma unroll
      for (int c = 0; c < 2; ++c) {
        int row = wm * 64 + mi * 16 + ql;
        af[mi][c] = *(const bf16x8*)(ab + row * 128 + (((c * 4 + g) ^ xr) * 16));
      }
    #pragma unroll
    for (int ni = 0; ni < 2; ++ni)
      #pragma unroll
      for (int c = 0; c < 2; ++c) {
        int row = wn * 32 + ni * 16 + ql;
        bfv[ni][c] = *(const bf16x8*)(wb + row * 128 + (((c * 4 + g) ^ xr) * 16));
      }
    __builtin_amdgcn_s_setprio(1);
    #pragma unroll
    for (int c = 0; c < 2; ++c)
      #pragma unroll
      for (int mi = 0; mi < 4; ++mi)
        #pragma unroll
        for (int ni = 0; ni < 2; ++ni)
          acc[mi][ni] = mfma16(af[mi][c], bfv[ni][c], acc[mi][ni]);
    __builtin_amdgcn_s_setprio(0);
    __builtin_amdgcn_s_barrier();
  }

  #pragma unroll
  for (int ni = 0; ni < 2; ++ni) {
    int n = n0 + wn * 32 + ni * 16 + ql;
    float bs = bias0[n];
    #pragma unroll
    for (int mi = 0; mi < 4; ++mi)
      #pragma unroll
      for (int i = 0; i < 4; ++i) {
        int m = m0 + wm * 64 + mi * 16 + g * 4 + i;
        outp[(size_t)m * HID_ + n] = acc[mi][ni][i] + bs;
      }
  }
}

// ---------------- flash attention: depth-2 prefetch + SINGLE barrier per iteration ------------
// Order per iter: [vmcnt(2); barrier; stage(t+2); compute(t)]. Safety: stage(t+2) writes buf
// (t-1)%3, whose readers (compute(t-1)) consumed their ds_reads before arriving at barrier(t).
// P-tile is per-wave. Epilogue scratch overlaps buf0 -> one __syncthreads after the loop.
__global__ __launch_bounds__(512, 6) void attn(const u16* __restrict__ Qp, const u16* __restrict__ KKp,
                                               const u16* __restrict__ Vt, const int* __restrict__ mask,
                                               u16* __restrict__ hidden) {
  __shared__ __align__(16) char smem[69632];   // bufs 0/1/2 @ i*16384 (K@+0,V@+8192); P@49152; madd@65536
  const int tid = threadIdx.x;
  const int lane = tid & 63, w = tid >> 6;     // w in 0..7
  const int g = lane >> 4, ql = lane & 15;
  const int bid = blockIdx.x;                  // 512 = 8 xcd x 8 bh-sub x 8 qt
  const int bh = (bid & 7) * 8 + ((bid >> 3) & 7);
  const int qt = bid >> 6;                     // 0..7
  const int b = bh >> 4, h = bh & 15;
  const int q0 = qt * 128;
  const int xr = ql & 7;
  const int o = tid * 16;
  const int srow = o >> 7, sch = (o >> 4) & 7;
  const size_t kgbase = (size_t)(b * S_ + srow) * HID_ + h * DH_ + ((sch ^ (srow & 7)) * 8);
  const size_t vgbase = (size_t)(bh * DH_ + srow) * S_ + ((sch ^ (srow & 7)) * 8);

  // prologue: stage tiles 0 and 1
  gload16(KKp + kgbase, smem + w * 1024);
  gload16(Vt + vgbase, smem + 8192 + w * 1024);
  gload16(KKp + kgbase + (size_t)64 * HID_, smem + 16384 + w * 1024);
  gload16(Vt + vgbase + 64, smem + 16384 + 8192 + w * 1024);
  // mask row -> additive f32 in LDS (once)
  {
    int2 mv2 = *(const int2*)(mask + b * S_ + tid * 2);
    float2 f;
    f.x = mv2.x ? 0.f : -1e9f;
    f.y = mv2.y ? 0.f : -1e9f;
    *(float2*)(smem + 65536 + tid * 8) = f;
  }

  const u16* qrow = Qp + (size_t)(b * S_ + q0 + w * 16 + ql) * HID_ + h * DH_;
  bf16x8 qb0 = *(const bf16x8*)(qrow + g * 8);
  bf16x8 qb1 = *(const bf16x8*)(qrow + 32 + g * 8);

  f32x4 oacc[4];
  #pragma unroll
  for (int d = 0; d < 4; ++d) oacc[d] = f32x4{0.f, 0.f, 0.f, 0.f};
  float m_run = -1e30f, l_run = 0.f;
  char* pbase = smem + 49152 + w * 2048 + ql * 128;
  const char* madd_l = smem + 65536;

  __syncthreads();   // publish madd; drains prologue stages (iter 0/1 waits trivially pass)

  int cur = 0, st = 2;
  #pragma unroll 1
  for (int it = 0; it < 16; ++it) {
    const int k0 = it * 64;
    if (it < 15) {
      asm volatile("s_waitcnt vmcnt(2)" ::: "memory");
    } else {
      asm volatile("s_waitcnt vmcnt(0)" ::: "memory");
    }
    __builtin_amdgcn_s_barrier();
    if (it < 14) {                       // stage tile t+2 AFTER barrier (buf (t-1)%3 is free)
      const int k0s = k0 + 128;
      const int bo = st * 16384;
      gload16(KKp + kgbase + (size_t)k0s * HID_, smem + bo + w * 1024);
      gload16(Vt + vgbase + k0s, smem + bo + 8192 + w * 1024);
    }

    const char* kb_ = smem + cur * 16384;
    const char* vb_ = smem + cur * 16384 + 8192;

    float sv[4][4];
    #pragma unroll
    for (int t = 0; t < 4; ++t) {
      const char* krow = kb_ + (16 * t + ql) * 128;
      bf16x8 ka0 = *(const bf16x8*)(krow + ((g ^ xr) * 16));
      bf16x8 ka1 = *(const bf16x8*)(krow + (((4 + g) ^ xr) * 16));
      f32x4 stv = mfma16(ka0, qb0, f32x4{0.f, 0.f, 0.f, 0.f});
      stv = mfma16(ka1, qb1, stv);
      f32x4 md = *(const f32x4*)(madd_l + (k0 + 16 * t + 4 * g) * 4);
      sv[t][0] = stv[0] + md[0];
      sv[t][1] = stv[1] + md[1];
      sv[t][2] = stv[2] + md[2];
      sv[t][3] = stv[3] + md[3];
    }
    float mloc = sv[0][0];
    #pragma unroll
    for (int t = 0; t < 4; ++t)
      #pragma unroll
      for (int i = 0; i < 4; ++i) mloc = fmaxf(mloc, sv[t][i]);
    mloc = fmaxf(mloc, __shfl_xor(mloc, 16, 64));
    mloc = fmaxf(mloc, __shfl_xor(mloc, 32, 64));
    if (__any(mloc > m_run + 10.f)) {
      float mnew = fmaxf(m_run, mloc);
      float alpha = __builtin_amdgcn_exp2f(m_run - mnew);
      l_run *= alpha;
      #pragma unroll
      for (int d = 0; d < 4; ++d) oacc[d] *= alpha;
      m_run = mnew;
    }
    float rsum = 0.f;
    float pvs[4][4];
    #pragma unroll
    for (int t = 0; t < 4; ++t)
      #pragma unroll
      for (int i = 0; i < 4; ++i) {
        float p = __builtin_amdgcn_exp2f(sv[t][i] - m_run);
        pvs[t][i] = p; rsum += p;
      }
    rsum += __shfl_xor(rsum, 16, 64);
    rsum += __shfl_xor(rsum, 32, 64);
    l_run += rsum;

    #pragma unroll
    for (int t = 0; t < 4; ++t) {
      uint2 pw;
      pw.x = cvtpk(pvs[t][0], pvs[t][1]);
      pw.y = cvtpk(pvs[t][2], pvs[t][3]);
      *(uint2*)(pbase + (((4 * t + g) ^ (2 * xr)) * 8)) = pw;
    }
    #pragma unroll
    for (int c = 0; c < 2; ++c) {
      bf16x8 pf = *(const bf16x8*)(pbase + (((c * 4 + g) ^ xr) * 16));
      #pragma unroll
      for (int d = 0; d < 4; ++d) {
        bf16x8 va = *(const bf16x8*)(vb_ + (16 * d + ql) * 128 + (((c * 4 + g) ^ xr) * 16));
        oacc[d] = mfma16(va, pf, oacc[d]);
      }
    }
    cur = (cur == 2) ? 0 : cur + 1;
    st  = (st == 2) ? 0 : st + 1;
  }
  __syncthreads();   // all waves done with K/V bufs before epilogue scratch overwrites them

  float inv = 1.0f / l_run;
  char* ep = smem + w * 2304;
  #pragma unroll
  for (int d = 0; d < 4; ++d)
    #pragma unroll
    for (int i = 0; i < 4; ++i)
      *(u16*)(ep + ql * 144 + (16 * d + 4 * g + i) * 2) = f2bf(oacc[d][i] * inv);
  __syncthreads();
  int r = lane >> 2, cc = lane & 3;
  const char* erow = smem + w * 2304 + r * 144 + cc * 32;
  uint4 v0 = *(const uint4*)erow;
  uint4 v1 = *(const uint4*)(erow + 16);
  u16* orow = hidden + (size_t)(b * S_ + q0 + w * 16 + r) * HID_ + h * DH_ + cc * 16;
  *(uint4*)orow = v0;
  *(uint4*)(orow + 8) = v1;
}

// ---------------- launch ----------------
extern "C" void kernel_launch(void* const* d_in, const int* in_sizes, int n_in,
                              void* d_out, int out_size, void* d_ws, size_t ws_size,
                              hipStream_t stream) {
  (void)in_sizes; (void)n_in; (void)out_size; (void)ws_size;
  const float* q    = (const float*)d_in[0];
  const float* k    = (const float*)d_in[1];
  const float* v    = (const float*)d_in[2];
  const float* kb   = (const float*)d_in[3];
  const int*   mask = (const int*)  d_in[4];
  const float* Wq   = (const float*)d_in[5];
  const float* bq   = (const float*)d_in[6];
  const float* Wk   = (const float*)d_in[7];
  const float* bk   = (const float*)d_in[8];
  const float* Wv   = (const float*)d_in[9];
  const float* bv   = (const float*)d_in[10];
  const float* Wkb  = (const float*)d_in[11];
  const float* bkb  = (const float*)d_in[12];
  const float* Wo   = (const float*)d_in[13];
  const float* bo   = (const float*)d_in[14];

  char* ws = (char*)d_ws;
  const size_t MB = 1024 * 1024;
  u16* qbf   = (u16*)(ws + 0 * MB);
  u16* kbf   = (u16*)(ws + 8 * MB);
  u16* vbf   = (u16*)(ws + 16 * MB);
  u16* kbbf  = (u16*)(ws + 24 * MB);
  u16* Wqbf  = (u16*)(ws + 32 * MB);
  u16* Wkbf  = (u16*)(ws + 34 * MB);
  u16* Wvbf  = (u16*)(ws + 36 * MB);
  u16* Wkbbf = (u16*)(ws + 38 * MB);
  u16* Wobf  = (u16*)(ws + 40 * MB);
  u16* Qp    = (u16*)(ws + 42 * MB);
  u16* KKp   = (u16*)(ws + 50 * MB);
  u16* Vtp   = (u16*)(ws + 58 * MB);
  u16* hid   = (u16*)(ws + 66 * MB);

  cvt_all<<<10752, 256, 0, stream>>>(q, k, v, kb, Wq, Wk, Wv, Wkb, Wo,
                                     qbf, kbf, vbf, kbbf, Wqbf, Wkbf, Wvbf, Wkbbf, Wobf);
  gemm_proj<<<1536, 256, 0, stream>>>(qbf, Wqbf, kbf, Wkbf, kbbf, Wkbbf, vbf, Wvbf,
                                      bq, bk, bkb, bv, Qp, KKp, Vtp);
  attn<<<512, 512, 0, stream>>>(Qp, KKp, Vtp, mask, hid);
  gemm_o<<<512, 256, 0, stream>>>(hid, Wobf, bo, (float*)d_out);
}